// Round 16
// baseline (745.480 us; speedup 1.0000x reference)
//
#include <hip/hip_runtime.h>
#include <hip/hip_bf16.h>
#include <math.h>

#define PN 20000
#define DN 20000
#define SEQK 1024
#define EPPI 640000
#define EDDI 640000
#define EDTI 400000
#define NPAIRN 100000
#define RPB 128            // rows per bucket
#define NBUCK 157          // ceil(20000/128)
#define CH 4096            // edges per sort block
#define NBLKMAX 157        // ceil(640000/4096)
#define RBX 40             // row-blocks per XCD = ceil(313/8)

typedef float4 f4;
using bf16x8 = __attribute__((ext_vector_type(8))) __bf16;
using bf16x4 = __attribute__((ext_vector_type(4))) __bf16;
using f32x4v = __attribute__((ext_vector_type(4))) float;

__device__ __forceinline__ f4 ld4(const float* p) { return *reinterpret_cast<const f4*>(p); }
__device__ __forceinline__ f4 ldb4(const __bf16* p) {
  bf16x4 v = *reinterpret_cast<const bf16x4*>(p);
  return make_float4((float)v[0], (float)v[1], (float)v[2], (float)v[3]);
}
__device__ __forceinline__ void stb4(__bf16* p, f4 v) {
  bf16x4 o;
  o[0] = (__bf16)v.x; o[1] = (__bf16)v.y; o[2] = (__bf16)v.z; o[3] = (__bf16)v.w;
  *reinterpret_cast<bf16x4*>(p) = o;
}
__device__ __forceinline__ void acc4(f4& a, f4 b) { a.x+=b.x; a.y+=b.y; a.z+=b.z; a.w+=b.w; }
__device__ __forceinline__ void acc4s(f4& a, f4 b, float s) { a.x+=s*b.x; a.y+=s*b.y; a.z+=s*b.z; a.w+=s*b.w; }

__device__ __forceinline__ void wave_ln(f4& x) {
  float s  = x.x + x.y + x.z + x.w;
  float ss = x.x*x.x + x.y*x.y + x.z*x.z + x.w*x.w;
#pragma unroll
  for (int o = 32; o; o >>= 1) { s += __shfl_xor(s, o, 64); ss += __shfl_xor(ss, o, 64); }
  float m = s * (1.f/256.f);
  float v = ss * (1.f/256.f) - m*m;
  float r = rsqrtf(v + 1e-5f);
  x.x = (x.x-m)*r; x.y = (x.y-m)*r; x.z = (x.z-m)*r; x.w = (x.w-m)*r;
}

// LN over 256 feats held as 8 floats/lane across a 32-lane half-wave.
__device__ __forceinline__ void ln8(float* v) {
  float s = 0.f, ss = 0.f;
#pragma unroll
  for (int i = 0; i < 8; ++i) { s += v[i]; ss += v[i]*v[i]; }
#pragma unroll
  for (int o = 16; o; o >>= 1) { s += __shfl_xor(s, o, 64); ss += __shfl_xor(ss, o, 64); }
  float m = s * (1.f/256.f);
  float var = ss * (1.f/256.f) - m*m;
  float r = rsqrtf(var + 1e-5f);
#pragma unroll
  for (int i = 0; i < 8; ++i) v[i] = (v[i]-m)*r;
}

// ---------------- fp32 -> bf16 converter (weights + embeddings, 19 jobs) ----------------
struct CPack { const float* src[19]; __bf16* dst[19]; int n[19]; };
__global__ __launch_bounds__(256) void convert_all(CPack p) {
  const int wi = blockIdx.y;
  const int n = p.n[wi];
  const float* s = p.src[wi];
  __bf16* d = p.dst[wi];
  for (int i = (blockIdx.x * 256 + threadIdx.x) * 4; i < n; i += gridDim.x * 256 * 4) {
    f4 v = ld4(s + i);
    stb4(d + i, v);
  }
}

// ---------------- contention-free two-level counting-sort CSR build ----------------
struct GPack {
  const int* src[4]; const int* dst[4]; int nE[4];
  int* col[4]; int* rowptr[4]; float* outdeg[4];  // dinvP,dinvD,icD,icP
  unsigned* stg[4];
  int* bh;      // [4][NBUCK][NBLKMAX]
  int* bbase;   // [4][NBUCK+1]
};

__global__ __launch_bounds__(256) void sort_hist(GPack g) {
  __shared__ int h[NBUCK];
  const int gi = blockIdx.y, blk = blockIdx.x;
  const int t = threadIdx.x;
  for (int i = t; i < NBUCK; i += 256) h[i] = 0;
  __syncthreads();
  const int base = blk * CH, nE = g.nE[gi];
  const int* dst = g.dst[gi];
#pragma unroll
  for (int i = 0; i < CH / 256; ++i) {
    int e = base + i * 256 + t;
    if (e < nE) atomicAdd(&h[dst[e] >> 7], 1);
  }
  __syncthreads();
  int* bh = g.bh + (size_t)gi * NBUCK * NBLKMAX;
  for (int i = t; i < NBUCK; i += 256) bh[i * NBLKMAX + blk] = h[i];
}

__global__ __launch_bounds__(1024) void sort_scan(GPack g) {
  __shared__ int sums[1024];
  const int gi = blockIdx.y;
  int* bh = g.bh + (size_t)gi * NBUCK * NBLKMAX;
  int* bbase = g.bbase + gi * (NBUCK + 1);
  const int L = NBUCK * NBLKMAX;
  const int t = threadIdx.x;
  const int chunk = (L + 1023) / 1024;
  const int b = t * chunk;
  const int e = min(b + chunk, L);
  int s = 0;
  for (int i = b; i < e; ++i) s += bh[i];
  sums[t] = s;
  __syncthreads();
  for (int o = 1; o < 1024; o <<= 1) {
    int u = (t >= o) ? sums[t - o] : 0;
    __syncthreads();
    sums[t] += u;
    __syncthreads();
  }
  int run = sums[t] - s;
  for (int i = b; i < e; ++i) {
    if (i % NBLKMAX == 0) bbase[i / NBLKMAX] = run;
    int old = bh[i];
    bh[i] = run;
    run += old;
  }
  if (t == 0) bbase[NBUCK] = g.nE[gi];
}

__global__ __launch_bounds__(256) void sort_scatter(GPack g) {
  __shared__ int cur[NBUCK];
  const int gi = blockIdx.y, blk = blockIdx.x;
  const int t = threadIdx.x;
  const int* bh = g.bh + (size_t)gi * NBUCK * NBLKMAX;
  for (int i = t; i < NBUCK; i += 256) cur[i] = bh[i * NBLKMAX + blk];
  __syncthreads();
  const int base = blk * CH, nE = g.nE[gi];
  const int* src = g.src[gi];
  const int* dst = g.dst[gi];
  unsigned* stg = g.stg[gi];
#pragma unroll
  for (int i = 0; i < CH / 256; ++i) {
    int e = base + i * 256 + t;
    if (e < nE) {
      int d = dst[e];
      int bkt = d >> 7;
      int pos = atomicAdd(&cur[bkt], 1);
      stg[pos] = ((unsigned)src[e] << 7) | (unsigned)(d & 127);
    }
  }
}

__global__ __launch_bounds__(256) void bucket_csr(GPack g) {
  const int gi = blockIdx.y;
  const int b = blockIdx.x;
  const int base = g.bbase[gi * (NBUCK + 1) + b];
  const int cnt  = g.bbase[gi * (NBUCK + 1) + b + 1] - base;
  __shared__ int h[RPB], sc[RPB];
  const int t = threadIdx.x;
  if (t < RPB) h[t] = 0;
  __syncthreads();
  const unsigned* st = g.stg[gi] + base;
  const int row0 = b * RPB;
  for (int i = t; i < cnt; i += 256) atomicAdd(&h[st[i] & 127u], 1);
  __syncthreads();
  if (t == 0) { int run = 0; for (int r = 0; r < RPB; ++r) { sc[r] = run; run += h[r]; } }
  __syncthreads();
  const int rows = min(RPB, PN - row0);
  if (t < rows) {
    g.rowptr[gi][row0 + t] = base + sc[t];
    float c = (float)h[t];
    g.outdeg[gi][row0 + t] = (gi < 2) ? rsqrtf(c + 1.f) : (1.f / fmaxf(c, 1.f));
  }
  if (b == 0 && t == 0) g.rowptr[gi][PN] = g.nE[gi];
  __syncthreads();
  if (t < RPB) h[t] = sc[t];
  __syncthreads();
  for (int i = t; i < cnt; i += 256) {
    unsigned v = st[i];
    int pos = atomicAdd(&h[v & 127u], 1);
    g.col[gi][base + pos] = (int)(v >> 7);
  }
}

// ---------------- batched GEMM v3: wave computes 64x32, block = 64 rows x 128 cols ----------------
struct GB {
  const __bf16* X[6]; int lda[6];
  const __bf16* Wt[6]; const float* bias[6]; const float* scale[6];
  __bf16* out[6]; int K[6]; int ostride[6]; int act[6]; int ncol[6];  // ncol = N/128
};

__global__ __launch_bounds__(256) void gemm_batch(GB gb) {
  const int y = blockIdx.y;
  const int colchunk = gb.ncol[y];
  const int bid = blockIdx.x;
  if (bid >= 8 * RBX * colchunk) return;
  const int xcd = bid & 7;
  const int j = bid >> 3;
  const int row_blk = xcd * RBX + j / colchunk;
  const int cc = j % colchunk;
  const int M = PN;
  if (row_blk * 64 >= M) return;

  const __bf16* X  = gb.X[y];
  const __bf16* Wt = gb.Wt[y];
  const float* bias = gb.bias[y];
  const float* scale = gb.scale[y];
  __bf16* outb = gb.out[y];
  const int lda = gb.lda[y];
  const int K = gb.K[y];
  const int ostride = gb.ostride[y];
  const int act = gb.act[y];

  const int tid = threadIdx.x;
  const int lane = tid & 63;
  const int w = tid >> 6;
  const int r0 = row_blk * 64;
  const int c0 = cc * 128 + w * 32;
  const int l15 = lane & 15;
  const int lk = (lane >> 4) * 8;

  f32x4v acc[4][2];
#pragma unroll
  for (int m = 0; m < 4; ++m)
#pragma unroll
    for (int n = 0; n < 2; ++n) { acc[m][n][0]=0.f; acc[m][n][1]=0.f; acc[m][n][2]=0.f; acc[m][n][3]=0.f; }

  const __bf16* xp[4];
  const __bf16* wp[2];
#pragma unroll
  for (int m = 0; m < 4; ++m) {
    int r = min(r0 + m * 16 + l15, M - 1);
    xp[m] = X + (size_t)r * lda + lk;
  }
#pragma unroll
  for (int n = 0; n < 2; ++n) {
    wp[n] = Wt + (size_t)(c0 + n * 16 + l15) * K + lk;
  }

#pragma unroll 2
  for (int k0 = 0; k0 < K; k0 += 32) {
    bf16x8 a[4], b[2];
#pragma unroll
    for (int m = 0; m < 4; ++m) a[m] = *reinterpret_cast<const bf16x8*>(xp[m] + k0);
#pragma unroll
    for (int n = 0; n < 2; ++n) b[n] = *reinterpret_cast<const bf16x8*>(wp[n] + k0);
#pragma unroll
    for (int m = 0; m < 4; ++m)
#pragma unroll
      for (int n = 0; n < 2; ++n)
        acc[m][n] = __builtin_amdgcn_mfma_f32_16x16x32_bf16(a[m], b[n], acc[m][n], 0, 0, 0);
  }

  const int rq = (lane >> 4) * 4;
#pragma unroll
  for (int m = 0; m < 4; ++m) {
#pragma unroll
    for (int i = 0; i < 4; ++i) {
      int row = r0 + m * 16 + rq + i;
      if (row >= M) continue;
#pragma unroll
      for (int n = 0; n < 2; ++n) {
        int col = c0 + n * 16 + l15;
        float v = acc[m][n][i];
        if (bias) v += bias[col];
        if (act == 1) v = fmaxf(v, 0.f);
        else if (act == 2) v = v > 0.f ? v : (expf(v) - 1.f);
        if (scale && col < 256) v *= scale[row];
        outb[(size_t)row * ostride + col] = (__bf16)v;
      }
    }
  }
}

// ---------------- batched fused GCN stage (mode 0) / ln_elu (mode 1) ----------------
struct SB {
  const int* rpG[4]; const int* clG[4]; const float* dinv[4];
  const __bf16* T[4]; int tstr[4];
  const float* gbias[4]; const float* linb[4];
  const int* rpS[4]; const int* clS[4]; const float* ic[4]; const __bf16* Pt[4];
  const float* lw[4]; const float* lb[4];
  __bf16* out[4]; int ostr[4]; int n[4]; int act[4]; int mode[4];
};

__global__ __launch_bounds__(256) void stage_batch(SB sb) {
  const int y = blockIdx.y;
  int row = (blockIdx.x * blockDim.x + threadIdx.x) >> 6;
  if (row >= sb.n[y]) return;
  int lane = threadIdx.x & 63;
  int o = lane * 4;
  const __bf16* T = sb.T[y];
  const int tstr = sb.tstr[y];
  __bf16* out = sb.out[y];
  const int ostr = sb.ostr[y];

  if (sb.mode[y] == 1) {   // fp = elu(LN(T_row))
    f4 x = ldb4(T + (size_t)row * tstr + o);
    wave_ln(x);
    x.x = x.x > 0.f ? x.x : expf(x.x)-1.f;
    x.y = x.y > 0.f ? x.y : expf(x.y)-1.f;
    x.z = x.z > 0.f ? x.z : expf(x.z)-1.f;
    x.w = x.w > 0.f ? x.w : expf(x.w)-1.f;
    stb4(out + (size_t)row * ostr + o, x);
    return;
  }

  const int* rpG = sb.rpG[y];
  const int* clG = sb.clG[y];
  const float* dinv = sb.dinv[y];
  float dd = dinv[row];

  // T is pre-scaled by dinv (t' rows); gacc = self + neighbors, x = dd*gacc.
  f4 gacc = ldb4(T + (size_t)row * tstr + o);

  int beg = rpG[row], end = rpG[row + 1];
  int j = beg;
  for (; j + 7 < end; j += 8) {
    int s[8];
    f4 tv[8];
#pragma unroll
    for (int q = 0; q < 8; ++q) s[q] = clG[j + q];
#pragma unroll
    for (int q = 0; q < 8; ++q) tv[q] = ldb4(T + (size_t)s[q] * tstr + o);
#pragma unroll
    for (int q = 0; q < 8; ++q) acc4(gacc, tv[q]);
  }
  for (; j < end; ++j) {
    acc4(gacc, ldb4(T + (size_t)clG[j] * tstr + o));
  }

  f4 x = make_float4(0.f, 0.f, 0.f, 0.f);
  acc4s(x, gacc, dd);

  if (sb.gbias[y]) acc4(x, ld4(sb.gbias[y] + o));
  if (sb.linb[y])  acc4(x, ld4(sb.linb[y] + o));
  acc4(x, ldb4(T + (size_t)row * tstr + 256 + o));   // lin half of TL

  if (sb.rpS[y]) {
    const int* rpS = sb.rpS[y];
    const int* clS = sb.clS[y];
    const __bf16* Pt = sb.Pt[y];
    f4 s4 = make_float4(0.f, 0.f, 0.f, 0.f);
    int sbg = rpS[row], se = rpS[row + 1];
    int k = sbg;
    for (; k + 7 < se; k += 8) {
      int s[8];
      f4 tv[8];
#pragma unroll
      for (int q = 0; q < 8; ++q) s[q] = clS[k + q];
#pragma unroll
      for (int q = 0; q < 8; ++q) tv[q] = ldb4(Pt + (size_t)s[q] * 256 + o);
#pragma unroll
      for (int q = 0; q < 8; ++q) acc4(s4, tv[q]);
    }
    for (; k < se; ++k) acc4(s4, ldb4(Pt + (size_t)clS[k] * 256 + o));
    acc4s(x, s4, sb.ic[y][row]);
  }

  wave_ln(x);
  if (sb.lw[y]) {
    f4 w = ld4(sb.lw[y] + o), b = ld4(sb.lb[y] + o);
    x.x = x.x*w.x + b.x; x.y = x.y*w.y + b.y; x.z = x.z*w.z + b.z; x.w = x.w*w.w + b.w;
  }
  if (sb.act[y] == 1) {
    x.x = fmaxf(x.x, 0.f); x.y = fmaxf(x.y, 0.f); x.z = fmaxf(x.z, 0.f); x.w = fmaxf(x.w, 0.f);
  }
  stb4(out + (size_t)row * ostr + o, x);
}

// ---------------- pair epilogue: one pair per 32-lane half-wave ----------------
__global__ __launch_bounds__(256) void pair_kernel(
    const __bf16* __restrict__ PK,
    const int* __restrict__ idx1, const int* __restrict__ idx2,
    const float* __restrict__ wR, const float* __restrict__ wI,
    float* __restrict__ out, int npair)
{
  int pid = (blockIdx.x * 256 + threadIdx.x) >> 5;
  if (pid >= npair) return;
  int l = threadIdx.x & 31;
  int f = l * 8;
  const __bf16* r1 = PK + (size_t)idx1[pid] * 1024;
  const __bf16* r2 = PK + (size_t)idx2[pid] * 1024;

  bf16x8 a0 = *reinterpret_cast<const bf16x8*>(r1 + f);
  bf16x8 a1 = *reinterpret_cast<const bf16x8*>(r1 + 256 + f);
  bf16x8 a2 = *reinterpret_cast<const bf16x8*>(r1 + 512 + f);
  bf16x8 a3 = *reinterpret_cast<const bf16x8*>(r1 + 768 + f);
  bf16x8 b0 = *reinterpret_cast<const bf16x8*>(r2 + f);
  bf16x8 b1 = *reinterpret_cast<const bf16x8*>(r2 + 256 + f);
  bf16x8 b2 = *reinterpret_cast<const bf16x8*>(r2 + 512 + f);
  bf16x8 b3 = *reinterpret_cast<const bf16x8*>(r2 + 768 + f);

  float R1[8], I1[8], R2[8], I2[8];
#pragma unroll
  for (int i = 0; i < 8; ++i) {
    R1[i] = (float)a0[i] + (float)b1[i];
    I1[i] = (float)a2[i] + (float)b3[i];
    R2[i] = (float)a3[i] + (float)b2[i];
    I2[i] = (float)a1[i] + (float)b0[i];
  }
  ln8(R1); ln8(I1); ln8(R2); ln8(I2);

  float R[8], I[8];
#pragma unroll
  for (int i = 0; i < 8; ++i) {
    R[i] = R1[i]*R2[i] - I1[i]*I2[i];
    I[i] = R1[i]*I2[i] + I1[i]*R2[i];
  }
  ln8(R); ln8(I);

  f4 wr0 = ld4(wR + f), wr1 = ld4(wR + f + 4);
  f4 wi0 = ld4(wI + f), wi1 = ld4(wI + f + 4);
  float wrv[8] = {wr0.x,wr0.y,wr0.z,wr0.w, wr1.x,wr1.y,wr1.z,wr1.w};
  float wiv[8] = {wi0.x,wi0.y,wi0.z,wi0.w, wi1.x,wi1.y,wi1.z,wi1.w};
  float t = 0.f;
#pragma unroll
  for (int i = 0; i < 8; ++i) t += R[i]*(wrv[i]-wiv[i]) + I[i]*(wrv[i]+wiv[i]);
#pragma unroll
  for (int o = 16; o; o >>= 1) t += __shfl_xor(t, o, 64);
  if (l == 0) out[pid] = 1.f / (1.f + expf(-t));
}

extern "C" void kernel_launch(void* const* d_in, const int* in_sizes, int n_in,
                              void* d_out, int out_size, void* d_ws, size_t ws_size,
                              hipStream_t stream) {
  (void)in_sizes; (void)n_in; (void)out_size; (void)ws_size;
  const float* seq        = (const float*)d_in[0];
  const int*   ppi        = (const int*)d_in[1];
  const int*   ddi        = (const int*)d_in[2];
  const int*   dti        = (const int*)d_in[3];
  const int*   idx1       = (const int*)d_in[4];
  const int*   idx2       = (const int*)d_in[5];
  const float* seq_init_W = (const float*)d_in[6];
  const float* gs1_gcn_W  = (const float*)d_in[7];
  const float* gs1_gcn_b  = (const float*)d_in[8];
  const float* gs1_lin_W  = (const float*)d_in[9];
  const float* gs1_ln_w   = (const float*)d_in[10];
  const float* gs1_ln_b   = (const float*)d_in[11];
  const float* gs2_gcn_W  = (const float*)d_in[12];
  const float* gs2_gcn_b  = (const float*)d_in[13];
  const float* gs2_lin_W  = (const float*)d_in[14];
  const float* gs2_ln_w   = (const float*)d_in[15];
  const float* gs2_ln_b   = (const float*)d_in[16];
  const float* drug_emb   = (const float*)d_in[17];
  const float* prot_emb   = (const float*)d_in[18];
  const float* pp1_W = (const float*)d_in[19]; const float* pp1_b = (const float*)d_in[20];
  const float* td1_W = (const float*)d_in[21]; const float* td1_b = (const float*)d_in[22];
  const float* pr1_W = (const float*)d_in[23]; const float* pr1_b = (const float*)d_in[24];
  const float* dd1_W = (const float*)d_in[25]; const float* dd1_b = (const float*)d_in[26];
  const float* dt1_W = (const float*)d_in[27]; const float* dt1_b = (const float*)d_in[28];
  const float* dr1_W = (const float*)d_in[29]; const float* dr1_b = (const float*)d_in[30];
  const float* pp2_W = (const float*)d_in[31]; const float* pp2_b = (const float*)d_in[32];
  const float* td2_W = (const float*)d_in[33]; const float* td2_b = (const float*)d_in[34];
  const float* pr2_W = (const float*)d_in[35]; const float* pr2_b = (const float*)d_in[36];
  const float* seq_fc_W  = (const float*)d_in[43];
  const float* skip_fc_W = (const float*)d_in[44];
  const float* wR = (const float*)d_in[45];
  const float* wI = (const float*)d_in[46];
  float* outp = (float*)d_out;

  // ---------------- workspace layout ----------------
  char* base = (char*)d_ws;
  unsigned* stgP  = (unsigned*)base;                 // EPPI
  unsigned* stgD  = stgP + EPPI;
  unsigned* stgTD = stgD + EDDI;
  unsigned* stgTP = stgTD + EDTI;
  int* colP  = (int*)(stgTP + EDTI);
  int* colD  = colP + EPPI;
  int* colTD = colD + EDDI;
  int* colTP = colTD + EDTI;
  int* rowptrP  = colTP + EDTI;
  int* rowptrD  = rowptrP + PN + 1;
  int* rowptrTD = rowptrD + PN + 1;
  int* rowptrTP = rowptrTD + PN + 1;
  float* dinvP = (float*)(rowptrTP + PN + 1);
  float* dinvD = dinvP + PN;
  float* icD   = dinvD + PN;
  float* icP   = icD + PN;
  int* bh    = (int*)(icP + PN);                     // 4*NBUCK*NBLKMAX
  int* bbase = bh + 4 * NBUCK * NBLKMAX;             // 4*(NBUCK+1)

  unsigned long long waddr = (unsigned long long)(bbase + 4 * (NBUCK + 1));
  waddr = (waddr + 63ULL) & ~63ULL;
  __bf16* wb = (__bf16*)waddr;
  __bf16* Wseq  = wb;                           // [256,1024]
  __bf16* pair0 = Wseq + 256*1024;              // each pair [512,256]
  __bf16* pair1 = pair0 + 512*256;
  __bf16* pair2 = pair1 + 512*256;
  __bf16* pair3 = pair2 + 512*256;
  __bf16* pair4 = pair3 + 512*256;
  __bf16* sing  = pair4 + 512*256;
  __bf16* Wdt1  = sing;
  __bf16* Wtd1  = sing + 65536;
  __bf16* Wtd2  = sing + 2*65536;
  __bf16* Wsfc  = sing + 3*65536;
  __bf16* Wskp  = sing + 4*65536;
  const size_t NB = (size_t)PN * 256;
  __bf16* Ed    = sing + 5*65536;               // [20000,256]
  __bf16* Ep    = Ed + NB;
  __bf16* TL0   = Ep + NB;                      // [20000,512]
  __bf16* TLd   = TL0 + (size_t)PN*512;         // [20000,512]
  __bf16* TLp   = TLd + (size_t)PN*512;         // [20000,512]
  __bf16* B0    = TLp + (size_t)PN*512;         // x_seq
  __bf16* Bh    = B0 + NB;                      // h
  __bf16* B4a   = Bh + NB;                      // proj_p (4d) -> P5 proj
  __bf16* B4b   = B4a + NB;                     // proj_d (4p)
  __bf16* B4e   = B4b + NB;                     // fp
  __bf16* PK    = B4e + NB;                     // [20000][1024]: x1 | xfp | p2 | xskip
  __bf16* Eseq  = PK;                           // alias, dead after G1
  __bf16* Bd    = PK + 0;                       // d, stride 1024 (slot0)
  __bf16* Bp    = PK + 512;                     // p, stride 1024 (slot2)

  const dim3 blk(256);
  const dim3 sgrid(NBLKMAX, 4);
  const dim3 bgrid(NBUCK, 4);
  const int SROWS = (PN + 3) / 4;      // 5000 blocks for stage jobs
  const int GMAX  = 8 * RBX * 4;       // 1280 blocks for colchunk<=4 gemm

  // ---- converts (1 launch, 19 jobs) ----
  {
    CPack p;
    const float* srcs[19] = { seq_init_W, gs1_gcn_W, gs1_lin_W, gs2_gcn_W, gs2_lin_W,
                              dd1_W, dr1_W, pp1_W, pr1_W, pp2_W, pr2_W,
                              dt1_W, td1_W, td2_W, seq_fc_W, skip_fc_W,
                              seq, drug_emb, prot_emb };
    __bf16* dsts[19] = { Wseq, pair0, pair0 + 65536, pair1, pair1 + 65536,
                         pair2, pair2 + 65536, pair3, pair3 + 65536, pair4, pair4 + 65536,
                         Wdt1, Wtd1, Wtd2, Wsfc, Wskp,
                         Eseq, Ed, Ep };
    for (int i = 0; i < 19; ++i) {
      p.src[i] = srcs[i]; p.dst[i] = dsts[i];
      p.n[i] = (i == 0) ? 256*1024 : (i == 16) ? PN*SEQK : (i >= 17) ? PN*256 : 256*256;
    }
    hipLaunchKernelGGL(convert_all, dim3(2048, 19), blk, 0, stream, p);
  }

  // ---- counting-sort CSR build ----
  GPack g;
  g.src[0] = ppi;        g.dst[0] = ppi + EPPI; g.nE[0] = EPPI;
  g.src[1] = ddi;        g.dst[1] = ddi + EDDI; g.nE[1] = EDDI;
  g.src[2] = dti + EDTI; g.dst[2] = dti;        g.nE[2] = EDTI;
  g.src[3] = dti;        g.dst[3] = dti + EDTI; g.nE[3] = EDTI;
  g.col[0] = colP;  g.col[1] = colD;  g.col[2] = colTD;  g.col[3] = colTP;
  g.rowptr[0] = rowptrP; g.rowptr[1] = rowptrD; g.rowptr[2] = rowptrTD; g.rowptr[3] = rowptrTP;
  g.outdeg[0] = dinvP; g.outdeg[1] = dinvD; g.outdeg[2] = icD; g.outdeg[3] = icP;
  g.stg[0] = stgP; g.stg[1] = stgD; g.stg[2] = stgTD; g.stg[3] = stgTP;
  g.bh = bh; g.bbase = bbase;

  hipLaunchKernelGGL(sort_hist,    sgrid, blk, 0, stream, g);
  hipLaunchKernelGGL(sort_scan,    dim3(1, 4), dim3(1024), 0, stream, g);
  hipLaunchKernelGGL(sort_scatter, sgrid, blk, 0, stream, g);
  hipLaunchKernelGGL(bucket_csr,   bgrid, blk, 0, stream, g);

  auto GJOB = [&](GB& b, int i, const __bf16* X, int lda, const __bf16* Wt, const float* bias,
                  const float* scale, __bf16* out, int K, int ostr, int act, int colchunk) {
    b.X[i]=X; b.lda[i]=lda; b.Wt[i]=Wt; b.bias[i]=bias; b.scale[i]=scale;
    b.out[i]=out; b.K[i]=K; b.ostride[i]=ostr; b.act[i]=act; b.ncol[i]=colchunk;
  };
  auto SJOB = [&](SB& s, int i, const int* rpG, const int* clG, const float* dv,
                  const __bf16* T, int tstr, const float* gb, const float* lnb,
                  const int* rpS, const int* clS, const float* ic, const __bf16* Pt,
                  const float* lw, const float* lb, __bf16* out, int ostr, int n, int act) {
    s.mode[i]=0; s.rpG[i]=rpG; s.clG[i]=clG; s.dinv[i]=dv; s.T[i]=T; s.tstr[i]=tstr;
    s.gbias[i]=gb; s.linb[i]=lnb; s.rpS[i]=rpS; s.clS[i]=clS; s.ic[i]=ic; s.Pt[i]=Pt;
    s.lw[i]=lw; s.lb[i]=lb; s.out[i]=out; s.ostr[i]=ostr; s.n[i]=n; s.act[i]=act;
  };
  auto LJOB = [&](SB& s, int i, const __bf16* T, int tstr, __bf16* out, int ostr, int n) {
    s.mode[i]=1; s.T[i]=T; s.tstr[i]=tstr; s.out[i]=out; s.ostr[i]=ostr; s.n[i]=n;
  };

  // ---- G1: 6 GEMMs (P1, 4d-t, 4d-proj, 4p-t, 4p-proj, xskip) ----
  {
    GB b{};
    GJOB(b, 0, Eseq, 1024, Wseq,  nullptr, nullptr, B0,       1024, 256,  1, 2);
    GJOB(b, 1, Ed,   256,  pair2, nullptr, dinvD,   TLd,      256,  512,  0, 4);
    GJOB(b, 2, Ep,   256,  Wdt1,  dt1_b,   nullptr, B4a,      256,  256,  0, 2);
    GJOB(b, 3, Ep,   256,  pair3, nullptr, dinvP,   TLp,      256,  512,  0, 4);
    GJOB(b, 4, Ed,   256,  Wtd1,  td1_b,   nullptr, B4b,      256,  256,  0, 2);
    GJOB(b, 5, Ep,   256,  Wskp,  nullptr, nullptr, PK + 768, 256,  1024, 0, 2);
    hipLaunchKernelGGL(gemm_batch, dim3(GMAX, 6), blk, 0, stream, b);
  }

  // ---- G2: 1 GEMM (P2-t) ----
  {
    GB b{};
    GJOB(b, 0, B0, 256, pair0, nullptr, dinvP, TL0, 256, 512, 0, 4);
    hipLaunchKernelGGL(gemm_batch, dim3(GMAX, 1), blk, 0, stream, b);
  }

  // ---- S1: stage{4d -> Bd, 4p -> Bp, gs1 -> Bh} + ln_elu{B0 -> B4e} ----
  {
    SB s{};
    SJOB(s, 0, rowptrD, colD, dinvD, TLd, 512, dd1_b, dr1_b,
         rowptrTD, colTD, icD, B4a, nullptr, nullptr, Bd, 1024, DN, 1);
    SJOB(s, 1, rowptrP, colP, dinvP, TLp, 512, pp1_b, pr1_b,
         rowptrTP, colTP, icP, B4b, nullptr, nullptr, Bp, 1024, PN, 1);
    SJOB(s, 2, rowptrP, colP, dinvP, TL0, 512, gs1_gcn_b, nullptr,
         nullptr, nullptr, nullptr, nullptr, gs1_ln_w, gs1_ln_b, Bh, 256, PN, 1);
    LJOB(s, 3, B0, 256, B4e, 256, PN);
    hipLaunchKernelGGL(stage_batch, dim3(SROWS, 4), blk, 0, stream, s);
  }

  // ---- G3: 4 GEMMs (P3-t, P5-t, P5-proj, xfp) ----
  {
    GB b{};
    GJOB(b, 0, Bh,  256,  pair1, nullptr, dinvP,   TLd,      256, 512,  0, 4);
    GJOB(b, 1, Bp,  1024, pair4, nullptr, dinvP,   TLp,      256, 512,  0, 4);
    GJOB(b, 2, Bd,  1024, Wtd2,  td2_b,   nullptr, B4a,      256, 256,  0, 2);
    GJOB(b, 3, B4e, 256,  Wsfc,  nullptr, nullptr, PK + 256, 256, 1024, 2, 2);
    hipLaunchKernelGGL(gemm_batch, dim3(GMAX, 4), blk, 0, stream, b);
  }

  // ---- S2: stage{gs2 -> PK slot0, P5 -> PK slot2} ----
  {
    SB s{};
    SJOB(s, 0, rowptrP, colP, dinvP, TLd, 512, gs2_gcn_b, nullptr,
         nullptr, nullptr, nullptr, nullptr, gs2_ln_w, gs2_ln_b, PK + 0, 1024, PN, 0);
    SJOB(s, 1, rowptrP, colP, dinvP, TLp, 512, pp2_b, pr2_b,
         rowptrTP, colTP, icP, B4a, nullptr, nullptr, PK + 512, 1024, PN, 0);
    hipLaunchKernelGGL(stage_batch, dim3(SROWS, 2), blk, 0, stream, s);
  }

  // ---- pair epilogue ----
  hipLaunchKernelGGL(pair_kernel, dim3((NPAIRN + 7) / 8), blk, 0, stream,
                     PK, idx1, idx2, wR, wI, outp, NPAIRN);
}

// Round 17
// 704.319 us; speedup vs baseline: 1.0584x; 1.0584x over previous
//
#include <hip/hip_runtime.h>
#include <hip/hip_bf16.h>
#include <math.h>

#define PN 20000
#define DN 20000
#define SEQK 1024
#define EPPI 640000
#define EDDI 640000
#define EDTI 400000
#define NPAIRN 100000
#define RPB 128            // rows per bucket
#define NBUCK 157          // ceil(20000/128)
#define CH 4096            // edges per sort block
#define NBLKMAX 157        // ceil(640000/4096)
#define RBX 40             // row-blocks per XCD = ceil(313/8)

typedef float4 f4;
using bf16x8 = __attribute__((ext_vector_type(8))) __bf16;
using bf16x4 = __attribute__((ext_vector_type(4))) __bf16;
using f32x4v = __attribute__((ext_vector_type(4))) float;

__device__ __forceinline__ f4 ld4(const float* p) { return *reinterpret_cast<const f4*>(p); }
__device__ __forceinline__ f4 ldb4(const __bf16* p) {
  bf16x4 v = *reinterpret_cast<const bf16x4*>(p);
  return make_float4((float)v[0], (float)v[1], (float)v[2], (float)v[3]);
}
__device__ __forceinline__ void stb4(__bf16* p, f4 v) {
  bf16x4 o;
  o[0] = (__bf16)v.x; o[1] = (__bf16)v.y; o[2] = (__bf16)v.z; o[3] = (__bf16)v.w;
  *reinterpret_cast<bf16x4*>(p) = o;
}
__device__ __forceinline__ void acc4(f4& a, f4 b) { a.x+=b.x; a.y+=b.y; a.z+=b.z; a.w+=b.w; }
__device__ __forceinline__ void acc4s(f4& a, f4 b, float s) { a.x+=s*b.x; a.y+=s*b.y; a.z+=s*b.z; a.w+=s*b.w; }

__device__ __forceinline__ void wave_ln(f4& x) {
  float s  = x.x + x.y + x.z + x.w;
  float ss = x.x*x.x + x.y*x.y + x.z*x.z + x.w*x.w;
#pragma unroll
  for (int o = 32; o; o >>= 1) { s += __shfl_xor(s, o, 64); ss += __shfl_xor(ss, o, 64); }
  float m = s * (1.f/256.f);
  float v = ss * (1.f/256.f) - m*m;
  float r = rsqrtf(v + 1e-5f);
  x.x = (x.x-m)*r; x.y = (x.y-m)*r; x.z = (x.z-m)*r; x.w = (x.w-m)*r;
}

// LN over 256 feats held as 8 floats/lane across a 32-lane half-wave.
__device__ __forceinline__ void ln8(float* v) {
  float s = 0.f, ss = 0.f;
#pragma unroll
  for (int i = 0; i < 8; ++i) { s += v[i]; ss += v[i]*v[i]; }
#pragma unroll
  for (int o = 16; o; o >>= 1) { s += __shfl_xor(s, o, 64); ss += __shfl_xor(ss, o, 64); }
  float m = s * (1.f/256.f);
  float var = ss * (1.f/256.f) - m*m;
  float r = rsqrtf(var + 1e-5f);
#pragma unroll
  for (int i = 0; i < 8; ++i) v[i] = (v[i]-m)*r;
}

// ---------------- fp32 -> bf16 converter (weights + embeddings, 19 jobs) ----------------
struct CPack { const float* src[19]; __bf16* dst[19]; int n[19]; };
__global__ __launch_bounds__(256) void convert_all(CPack p) {
  const int wi = blockIdx.y;
  const int n = p.n[wi];
  const float* s = p.src[wi];
  __bf16* d = p.dst[wi];
  for (int i = (blockIdx.x * 256 + threadIdx.x) * 4; i < n; i += gridDim.x * 256 * 4) {
    f4 v = ld4(s + i);
    stb4(d + i, v);
  }
}

// ---------------- contention-free two-level counting-sort CSR build ----------------
struct GPack {
  const int* src[4]; const int* dst[4]; int nE[4];
  int* col[4]; int* rowptr[4]; float* outdeg[4];  // dinvP,dinvD,icD,icP
  unsigned* stg[4];
  int* bh;      // [4][NBUCK][NBLKMAX]
  int* bbase;   // [4][NBUCK+1]
};

__global__ __launch_bounds__(256) void sort_hist(GPack g) {
  __shared__ int h[NBUCK];
  const int gi = blockIdx.y, blk = blockIdx.x;
  const int t = threadIdx.x;
  for (int i = t; i < NBUCK; i += 256) h[i] = 0;
  __syncthreads();
  const int base = blk * CH, nE = g.nE[gi];
  const int* dst = g.dst[gi];
#pragma unroll
  for (int i = 0; i < CH / 256; ++i) {
    int e = base + i * 256 + t;
    if (e < nE) atomicAdd(&h[dst[e] >> 7], 1);
  }
  __syncthreads();
  int* bh = g.bh + (size_t)gi * NBUCK * NBLKMAX;
  for (int i = t; i < NBUCK; i += 256) bh[i * NBLKMAX + blk] = h[i];
}

__global__ __launch_bounds__(1024) void sort_scan(GPack g) {
  __shared__ int sums[1024];
  const int gi = blockIdx.y;
  int* bh = g.bh + (size_t)gi * NBUCK * NBLKMAX;
  int* bbase = g.bbase + gi * (NBUCK + 1);
  const int L = NBUCK * NBLKMAX;
  const int t = threadIdx.x;
  const int chunk = (L + 1023) / 1024;
  const int b = t * chunk;
  const int e = min(b + chunk, L);
  int s = 0;
  for (int i = b; i < e; ++i) s += bh[i];
  sums[t] = s;
  __syncthreads();
  for (int o = 1; o < 1024; o <<= 1) {
    int u = (t >= o) ? sums[t - o] : 0;
    __syncthreads();
    sums[t] += u;
    __syncthreads();
  }
  int run = sums[t] - s;
  for (int i = b; i < e; ++i) {
    if (i % NBLKMAX == 0) bbase[i / NBLKMAX] = run;
    int old = bh[i];
    bh[i] = run;
    run += old;
  }
  if (t == 0) bbase[NBUCK] = g.nE[gi];
}

__global__ __launch_bounds__(256) void sort_scatter(GPack g) {
  __shared__ int cur[NBUCK];
  const int gi = blockIdx.y, blk = blockIdx.x;
  const int t = threadIdx.x;
  const int* bh = g.bh + (size_t)gi * NBUCK * NBLKMAX;
  for (int i = t; i < NBUCK; i += 256) cur[i] = bh[i * NBLKMAX + blk];
  __syncthreads();
  const int base = blk * CH, nE = g.nE[gi];
  const int* src = g.src[gi];
  const int* dst = g.dst[gi];
  unsigned* stg = g.stg[gi];
#pragma unroll
  for (int i = 0; i < CH / 256; ++i) {
    int e = base + i * 256 + t;
    if (e < nE) {
      int d = dst[e];
      int bkt = d >> 7;
      int pos = atomicAdd(&cur[bkt], 1);
      stg[pos] = ((unsigned)src[e] << 7) | (unsigned)(d & 127);
    }
  }
}

__global__ __launch_bounds__(256) void bucket_csr(GPack g) {
  const int gi = blockIdx.y;
  const int b = blockIdx.x;
  const int base = g.bbase[gi * (NBUCK + 1) + b];
  const int cnt  = g.bbase[gi * (NBUCK + 1) + b + 1] - base;
  __shared__ int h[RPB], sc[RPB];
  const int t = threadIdx.x;
  if (t < RPB) h[t] = 0;
  __syncthreads();
  const unsigned* st = g.stg[gi] + base;
  const int row0 = b * RPB;
  for (int i = t; i < cnt; i += 256) atomicAdd(&h[st[i] & 127u], 1);
  __syncthreads();
  if (t == 0) { int run = 0; for (int r = 0; r < RPB; ++r) { sc[r] = run; run += h[r]; } }
  __syncthreads();
  const int rows = min(RPB, PN - row0);
  if (t < rows) {
    g.rowptr[gi][row0 + t] = base + sc[t];
    float c = (float)h[t];
    g.outdeg[gi][row0 + t] = (gi < 2) ? rsqrtf(c + 1.f) : (1.f / fmaxf(c, 1.f));
  }
  if (b == 0 && t == 0) g.rowptr[gi][PN] = g.nE[gi];
  __syncthreads();
  if (t < RPB) h[t] = sc[t];
  __syncthreads();
  for (int i = t; i < cnt; i += 256) {
    unsigned v = st[i];
    int pos = atomicAdd(&h[v & 127u], 1);
    g.col[gi][base + pos] = (int)(v >> 7);
  }
}

// ---------------- batched GEMM v2: wave computes 64x64, block = 64 rows x 256 cols ----------------
struct GB {
  const __bf16* X[6]; int lda[6];
  const __bf16* Wt[6]; const float* bias[6]; const float* scale[6];
  __bf16* out[6]; int K[6]; int ostride[6]; int act[6]; int ncol[6];  // ncol = N/256
};

__global__ __launch_bounds__(256) void gemm_batch(GB gb) {
  const int y = blockIdx.y;
  const int colchunk = gb.ncol[y];
  const int bid = blockIdx.x;
  if (bid >= 8 * RBX * colchunk) return;
  const int xcd = bid & 7;
  const int j = bid >> 3;
  const int row_blk = xcd * RBX + j / colchunk;
  const int cc = j % colchunk;
  const int M = PN;
  if (row_blk * 64 >= M) return;

  const __bf16* X  = gb.X[y];
  const __bf16* Wt = gb.Wt[y];
  const float* bias = gb.bias[y];
  const float* scale = gb.scale[y];
  __bf16* outb = gb.out[y];
  const int lda = gb.lda[y];
  const int K = gb.K[y];
  const int ostride = gb.ostride[y];
  const int act = gb.act[y];

  const int tid = threadIdx.x;
  const int lane = tid & 63;
  const int w = tid >> 6;
  const int r0 = row_blk * 64;
  const int c0 = cc * 256 + w * 64;
  const int l15 = lane & 15;
  const int lk = (lane >> 4) * 8;

  f32x4v acc[4][4];
#pragma unroll
  for (int m = 0; m < 4; ++m)
#pragma unroll
    for (int n = 0; n < 4; ++n) { acc[m][n][0]=0.f; acc[m][n][1]=0.f; acc[m][n][2]=0.f; acc[m][n][3]=0.f; }

  const __bf16* xp[4];
  const __bf16* wp[4];
#pragma unroll
  for (int m = 0; m < 4; ++m) {
    int r = min(r0 + m * 16 + l15, M - 1);
    xp[m] = X + (size_t)r * lda + lk;
  }
#pragma unroll
  for (int n = 0; n < 4; ++n) {
    wp[n] = Wt + (size_t)(c0 + n * 16 + l15) * K + lk;
  }

#pragma unroll 2
  for (int k0 = 0; k0 < K; k0 += 32) {
    bf16x8 a[4], b[4];
#pragma unroll
    for (int m = 0; m < 4; ++m) a[m] = *reinterpret_cast<const bf16x8*>(xp[m] + k0);
#pragma unroll
    for (int n = 0; n < 4; ++n) b[n] = *reinterpret_cast<const bf16x8*>(wp[n] + k0);
#pragma unroll
    for (int m = 0; m < 4; ++m)
#pragma unroll
      for (int n = 0; n < 4; ++n)
        acc[m][n] = __builtin_amdgcn_mfma_f32_16x16x32_bf16(a[m], b[n], acc[m][n], 0, 0, 0);
  }

  const int rq = (lane >> 4) * 4;
#pragma unroll
  for (int m = 0; m < 4; ++m) {
#pragma unroll
    for (int i = 0; i < 4; ++i) {
      int row = r0 + m * 16 + rq + i;
      if (row >= M) continue;
#pragma unroll
      for (int n = 0; n < 4; ++n) {
        int col = c0 + n * 16 + l15;
        float v = acc[m][n][i];
        if (bias) v += bias[col];
        if (act == 1) v = fmaxf(v, 0.f);
        else if (act == 2) v = v > 0.f ? v : (expf(v) - 1.f);
        if (scale && col < 256) v *= scale[row];
        outb[(size_t)row * ostride + col] = (__bf16)v;
      }
    }
  }
}

// ---------------- batched fused GCN stage (mode 0) / ln_elu (mode 1) ----------------
struct SB {
  const int* rpG[4]; const int* clG[4]; const float* dinv[4];
  const __bf16* T[4]; int tstr[4];
  const float* gbias[4]; const float* linb[4];
  const int* rpS[4]; const int* clS[4]; const float* ic[4]; const __bf16* Pt[4];
  const float* lw[4]; const float* lb[4];
  __bf16* out[4]; int ostr[4]; int n[4]; int act[4]; int mode[4];
};

__global__ __launch_bounds__(256) void stage_batch(SB sb) {
  const int y = blockIdx.y;
  int row = (blockIdx.x * blockDim.x + threadIdx.x) >> 6;
  if (row >= sb.n[y]) return;
  int lane = threadIdx.x & 63;
  int o = lane * 4;
  const __bf16* T = sb.T[y];
  const int tstr = sb.tstr[y];
  __bf16* out = sb.out[y];
  const int ostr = sb.ostr[y];

  if (sb.mode[y] == 1) {   // fp = elu(LN(T_row))
    f4 x = ldb4(T + (size_t)row * tstr + o);
    wave_ln(x);
    x.x = x.x > 0.f ? x.x : expf(x.x)-1.f;
    x.y = x.y > 0.f ? x.y : expf(x.y)-1.f;
    x.z = x.z > 0.f ? x.z : expf(x.z)-1.f;
    x.w = x.w > 0.f ? x.w : expf(x.w)-1.f;
    stb4(out + (size_t)row * ostr + o, x);
    return;
  }

  const int* rpG = sb.rpG[y];
  const int* clG = sb.clG[y];
  const float* dinv = sb.dinv[y];
  float dd = dinv[row];

  // T is pre-scaled by dinv (t' rows); gacc = self + neighbors, x = dd*gacc.
  f4 gacc = ldb4(T + (size_t)row * tstr + o);

  int beg = rpG[row], end = rpG[row + 1];
  int j = beg;
  for (; j + 7 < end; j += 8) {
    int s[8];
    f4 tv[8];
#pragma unroll
    for (int q = 0; q < 8; ++q) s[q] = clG[j + q];
#pragma unroll
    for (int q = 0; q < 8; ++q) tv[q] = ldb4(T + (size_t)s[q] * tstr + o);
#pragma unroll
    for (int q = 0; q < 8; ++q) acc4(gacc, tv[q]);
  }
  for (; j < end; ++j) {
    acc4(gacc, ldb4(T + (size_t)clG[j] * tstr + o));
  }

  f4 x = make_float4(0.f, 0.f, 0.f, 0.f);
  acc4s(x, gacc, dd);

  if (sb.gbias[y]) acc4(x, ld4(sb.gbias[y] + o));
  if (sb.linb[y])  acc4(x, ld4(sb.linb[y] + o));
  acc4(x, ldb4(T + (size_t)row * tstr + 256 + o));   // lin half of TL

  if (sb.rpS[y]) {
    const int* rpS = sb.rpS[y];
    const int* clS = sb.clS[y];
    const __bf16* Pt = sb.Pt[y];
    f4 s4 = make_float4(0.f, 0.f, 0.f, 0.f);
    int sbg = rpS[row], se = rpS[row + 1];
    int k = sbg;
    for (; k + 7 < se; k += 8) {
      int s[8];
      f4 tv[8];
#pragma unroll
      for (int q = 0; q < 8; ++q) s[q] = clS[k + q];
#pragma unroll
      for (int q = 0; q < 8; ++q) tv[q] = ldb4(Pt + (size_t)s[q] * 256 + o);
#pragma unroll
      for (int q = 0; q < 8; ++q) acc4(s4, tv[q]);
    }
    for (; k < se; ++k) acc4(s4, ldb4(Pt + (size_t)clS[k] * 256 + o));
    acc4s(x, s4, sb.ic[y][row]);
  }

  wave_ln(x);
  if (sb.lw[y]) {
    f4 w = ld4(sb.lw[y] + o), b = ld4(sb.lb[y] + o);
    x.x = x.x*w.x + b.x; x.y = x.y*w.y + b.y; x.z = x.z*w.z + b.z; x.w = x.w*w.w + b.w;
  }
  if (sb.act[y] == 1) {
    x.x = fmaxf(x.x, 0.f); x.y = fmaxf(x.y, 0.f); x.z = fmaxf(x.z, 0.f); x.w = fmaxf(x.w, 0.f);
  }
  stb4(out + (size_t)row * ostr + o, x);
}

// ---------------- pair epilogue: one pair per 32-lane half-wave ----------------
__global__ __launch_bounds__(256) void pair_kernel(
    const __bf16* __restrict__ PK,
    const int* __restrict__ idx1, const int* __restrict__ idx2,
    const float* __restrict__ wR, const float* __restrict__ wI,
    float* __restrict__ out, int npair)
{
  int pid = (blockIdx.x * 256 + threadIdx.x) >> 5;
  if (pid >= npair) return;
  int l = threadIdx.x & 31;
  int f = l * 8;
  const __bf16* r1 = PK + (size_t)idx1[pid] * 1024;
  const __bf16* r2 = PK + (size_t)idx2[pid] * 1024;

  bf16x8 a0 = *reinterpret_cast<const bf16x8*>(r1 + f);
  bf16x8 a1 = *reinterpret_cast<const bf16x8*>(r1 + 256 + f);
  bf16x8 a2 = *reinterpret_cast<const bf16x8*>(r1 + 512 + f);
  bf16x8 a3 = *reinterpret_cast<const bf16x8*>(r1 + 768 + f);
  bf16x8 b0 = *reinterpret_cast<const bf16x8*>(r2 + f);
  bf16x8 b1 = *reinterpret_cast<const bf16x8*>(r2 + 256 + f);
  bf16x8 b2 = *reinterpret_cast<const bf16x8*>(r2 + 512 + f);
  bf16x8 b3 = *reinterpret_cast<const bf16x8*>(r2 + 768 + f);

  float R1[8], I1[8], R2[8], I2[8];
#pragma unroll
  for (int i = 0; i < 8; ++i) {
    R1[i] = (float)a0[i] + (float)b1[i];
    I1[i] = (float)a2[i] + (float)b3[i];
    R2[i] = (float)a3[i] + (float)b2[i];
    I2[i] = (float)a1[i] + (float)b0[i];
  }
  ln8(R1); ln8(I1); ln8(R2); ln8(I2);

  float R[8], I[8];
#pragma unroll
  for (int i = 0; i < 8; ++i) {
    R[i] = R1[i]*R2[i] - I1[i]*I2[i];
    I[i] = R1[i]*I2[i] + I1[i]*R2[i];
  }
  ln8(R); ln8(I);

  f4 wr0 = ld4(wR + f), wr1 = ld4(wR + f + 4);
  f4 wi0 = ld4(wI + f), wi1 = ld4(wI + f + 4);
  float wrv[8] = {wr0.x,wr0.y,wr0.z,wr0.w, wr1.x,wr1.y,wr1.z,wr1.w};
  float wiv[8] = {wi0.x,wi0.y,wi0.z,wi0.w, wi1.x,wi1.y,wi1.z,wi1.w};
  float t = 0.f;
#pragma unroll
  for (int i = 0; i < 8; ++i) t += R[i]*(wrv[i]-wiv[i]) + I[i]*(wrv[i]+wiv[i]);
#pragma unroll
  for (int o = 16; o; o >>= 1) t += __shfl_xor(t, o, 64);
  if (l == 0) out[pid] = 1.f / (1.f + expf(-t));
}

extern "C" void kernel_launch(void* const* d_in, const int* in_sizes, int n_in,
                              void* d_out, int out_size, void* d_ws, size_t ws_size,
                              hipStream_t stream) {
  (void)in_sizes; (void)n_in; (void)out_size; (void)ws_size;
  const float* seq        = (const float*)d_in[0];
  const int*   ppi        = (const int*)d_in[1];
  const int*   ddi        = (const int*)d_in[2];
  const int*   dti        = (const int*)d_in[3];
  const int*   idx1       = (const int*)d_in[4];
  const int*   idx2       = (const int*)d_in[5];
  const float* seq_init_W = (const float*)d_in[6];
  const float* gs1_gcn_W  = (const float*)d_in[7];
  const float* gs1_gcn_b  = (const float*)d_in[8];
  const float* gs1_lin_W  = (const float*)d_in[9];
  const float* gs1_ln_w   = (const float*)d_in[10];
  const float* gs1_ln_b   = (const float*)d_in[11];
  const float* gs2_gcn_W  = (const float*)d_in[12];
  const float* gs2_gcn_b  = (const float*)d_in[13];
  const float* gs2_lin_W  = (const float*)d_in[14];
  const float* gs2_ln_w   = (const float*)d_in[15];
  const float* gs2_ln_b   = (const float*)d_in[16];
  const float* drug_emb   = (const float*)d_in[17];
  const float* prot_emb   = (const float*)d_in[18];
  const float* pp1_W = (const float*)d_in[19]; const float* pp1_b = (const float*)d_in[20];
  const float* td1_W = (const float*)d_in[21]; const float* td1_b = (const float*)d_in[22];
  const float* pr1_W = (const float*)d_in[23]; const float* pr1_b = (const float*)d_in[24];
  const float* dd1_W = (const float*)d_in[25]; const float* dd1_b = (const float*)d_in[26];
  const float* dt1_W = (const float*)d_in[27]; const float* dt1_b = (const float*)d_in[28];
  const float* dr1_W = (const float*)d_in[29]; const float* dr1_b = (const float*)d_in[30];
  const float* pp2_W = (const float*)d_in[31]; const float* pp2_b = (const float*)d_in[32];
  const float* td2_W = (const float*)d_in[33]; const float* td2_b = (const float*)d_in[34];
  const float* pr2_W = (const float*)d_in[35]; const float* pr2_b = (const float*)d_in[36];
  const float* seq_fc_W  = (const float*)d_in[43];
  const float* skip_fc_W = (const float*)d_in[44];
  const float* wR = (const float*)d_in[45];
  const float* wI = (const float*)d_in[46];
  float* outp = (float*)d_out;

  // ---------------- workspace layout ----------------
  char* base = (char*)d_ws;
  unsigned* stgP  = (unsigned*)base;                 // EPPI
  unsigned* stgD  = stgP + EPPI;
  unsigned* stgTD = stgD + EDDI;
  unsigned* stgTP = stgTD + EDTI;
  int* colP  = (int*)(stgTP + EDTI);
  int* colD  = colP + EPPI;
  int* colTD = colD + EDDI;
  int* colTP = colTD + EDTI;
  int* rowptrP  = colTP + EDTI;
  int* rowptrD  = rowptrP + PN + 1;
  int* rowptrTD = rowptrD + PN + 1;
  int* rowptrTP = rowptrTD + PN + 1;
  float* dinvP = (float*)(rowptrTP + PN + 1);
  float* dinvD = dinvP + PN;
  float* icD   = dinvD + PN;
  float* icP   = icD + PN;
  int* bh    = (int*)(icP + PN);                     // 4*NBUCK*NBLKMAX
  int* bbase = bh + 4 * NBUCK * NBLKMAX;             // 4*(NBUCK+1)

  unsigned long long waddr = (unsigned long long)(bbase + 4 * (NBUCK + 1));
  waddr = (waddr + 63ULL) & ~63ULL;
  __bf16* wb = (__bf16*)waddr;
  __bf16* Wseq  = wb;                           // [256,1024]
  __bf16* pair0 = Wseq + 256*1024;              // each pair [512,256]
  __bf16* pair1 = pair0 + 512*256;
  __bf16* pair2 = pair1 + 512*256;
  __bf16* pair3 = pair2 + 512*256;
  __bf16* pair4 = pair3 + 512*256;
  __bf16* sing  = pair4 + 512*256;
  __bf16* Wdt1  = sing;
  __bf16* Wtd1  = sing + 65536;
  __bf16* Wtd2  = sing + 2*65536;
  __bf16* Wsfc  = sing + 3*65536;
  __bf16* Wskp  = sing + 4*65536;
  const size_t NB = (size_t)PN * 256;
  __bf16* Ed    = sing + 5*65536;               // [20000,256]
  __bf16* Ep    = Ed + NB;
  __bf16* TL0   = Ep + NB;                      // [20000,512]
  __bf16* TLd   = TL0 + (size_t)PN*512;         // [20000,512]
  __bf16* TLp   = TLd + (size_t)PN*512;         // [20000,512]
  __bf16* B0    = TLp + (size_t)PN*512;         // x_seq
  __bf16* Bh    = B0 + NB;                      // h
  __bf16* B4a   = Bh + NB;                      // proj_p (4d) -> P5 proj
  __bf16* B4b   = B4a + NB;                     // proj_d (4p)
  __bf16* B4e   = B4b + NB;                     // fp
  __bf16* PK    = B4e + NB;                     // [20000][1024]: x1 | xfp | p2 | xskip
  __bf16* Eseq  = PK;                           // alias, dead after G1
  __bf16* Bd    = PK + 0;                       // d, stride 1024 (slot0)
  __bf16* Bp    = PK + 512;                     // p, stride 1024 (slot2)

  const dim3 blk(256);
  const dim3 sgrid(NBLKMAX, 4);
  const dim3 bgrid(NBUCK, 4);
  const int SROWS = (PN + 3) / 4;      // 5000 blocks for stage jobs
  const int GMAX  = 8 * RBX * 2;       // 640 blocks for colchunk<=2 gemm

  // ---- converts (1 launch, 19 jobs) ----
  {
    CPack p;
    const float* srcs[19] = { seq_init_W, gs1_gcn_W, gs1_lin_W, gs2_gcn_W, gs2_lin_W,
                              dd1_W, dr1_W, pp1_W, pr1_W, pp2_W, pr2_W,
                              dt1_W, td1_W, td2_W, seq_fc_W, skip_fc_W,
                              seq, drug_emb, prot_emb };
    __bf16* dsts[19] = { Wseq, pair0, pair0 + 65536, pair1, pair1 + 65536,
                         pair2, pair2 + 65536, pair3, pair3 + 65536, pair4, pair4 + 65536,
                         Wdt1, Wtd1, Wtd2, Wsfc, Wskp,
                         Eseq, Ed, Ep };
    for (int i = 0; i < 19; ++i) {
      p.src[i] = srcs[i]; p.dst[i] = dsts[i];
      p.n[i] = (i == 0) ? 256*1024 : (i == 16) ? PN*SEQK : (i >= 17) ? PN*256 : 256*256;
    }
    hipLaunchKernelGGL(convert_all, dim3(2048, 19), blk, 0, stream, p);
  }

  // ---- counting-sort CSR build ----
  GPack g;
  g.src[0] = ppi;        g.dst[0] = ppi + EPPI; g.nE[0] = EPPI;
  g.src[1] = ddi;        g.dst[1] = ddi + EDDI; g.nE[1] = EDDI;
  g.src[2] = dti + EDTI; g.dst[2] = dti;        g.nE[2] = EDTI;
  g.src[3] = dti;        g.dst[3] = dti + EDTI; g.nE[3] = EDTI;
  g.col[0] = colP;  g.col[1] = colD;  g.col[2] = colTD;  g.col[3] = colTP;
  g.rowptr[0] = rowptrP; g.rowptr[1] = rowptrD; g.rowptr[2] = rowptrTD; g.rowptr[3] = rowptrTP;
  g.outdeg[0] = dinvP; g.outdeg[1] = dinvD; g.outdeg[2] = icD; g.outdeg[3] = icP;
  g.stg[0] = stgP; g.stg[1] = stgD; g.stg[2] = stgTD; g.stg[3] = stgTP;
  g.bh = bh; g.bbase = bbase;

  hipLaunchKernelGGL(sort_hist,    sgrid, blk, 0, stream, g);
  hipLaunchKernelGGL(sort_scan,    dim3(1, 4), dim3(1024), 0, stream, g);
  hipLaunchKernelGGL(sort_scatter, sgrid, blk, 0, stream, g);
  hipLaunchKernelGGL(bucket_csr,   bgrid, blk, 0, stream, g);

  auto GJOB = [&](GB& b, int i, const __bf16* X, int lda, const __bf16* Wt, const float* bias,
                  const float* scale, __bf16* out, int K, int ostr, int act, int colchunk) {
    b.X[i]=X; b.lda[i]=lda; b.Wt[i]=Wt; b.bias[i]=bias; b.scale[i]=scale;
    b.out[i]=out; b.K[i]=K; b.ostride[i]=ostr; b.act[i]=act; b.ncol[i]=colchunk;
  };
  auto SJOB = [&](SB& s, int i, const int* rpG, const int* clG, const float* dv,
                  const __bf16* T, int tstr, const float* gb, const float* lnb,
                  const int* rpS, const int* clS, const float* ic, const __bf16* Pt,
                  const float* lw, const float* lb, __bf16* out, int ostr, int n, int act) {
    s.mode[i]=0; s.rpG[i]=rpG; s.clG[i]=clG; s.dinv[i]=dv; s.T[i]=T; s.tstr[i]=tstr;
    s.gbias[i]=gb; s.linb[i]=lnb; s.rpS[i]=rpS; s.clS[i]=clS; s.ic[i]=ic; s.Pt[i]=Pt;
    s.lw[i]=lw; s.lb[i]=lb; s.out[i]=out; s.ostr[i]=ostr; s.n[i]=n; s.act[i]=act;
  };
  auto LJOB = [&](SB& s, int i, const __bf16* T, int tstr, __bf16* out, int ostr, int n) {
    s.mode[i]=1; s.T[i]=T; s.tstr[i]=tstr; s.out[i]=out; s.ostr[i]=ostr; s.n[i]=n;
  };

  // ---- G1: 6 GEMMs (P1, 4d-t, 4d-proj, 4p-t, 4p-proj, xskip) ----
  {
    GB b{};
    GJOB(b, 0, Eseq, 1024, Wseq,  nullptr, nullptr, B0,       1024, 256,  1, 1);
    GJOB(b, 1, Ed,   256,  pair2, nullptr, dinvD,   TLd,      256,  512,  0, 2);
    GJOB(b, 2, Ep,   256,  Wdt1,  dt1_b,   nullptr, B4a,      256,  256,  0, 1);
    GJOB(b, 3, Ep,   256,  pair3, nullptr, dinvP,   TLp,      256,  512,  0, 2);
    GJOB(b, 4, Ed,   256,  Wtd1,  td1_b,   nullptr, B4b,      256,  256,  0, 1);
    GJOB(b, 5, Ep,   256,  Wskp,  nullptr, nullptr, PK + 768, 256,  1024, 0, 1);
    hipLaunchKernelGGL(gemm_batch, dim3(GMAX, 6), blk, 0, stream, b);
  }

  // ---- G2: 1 GEMM (P2-t) ----
  {
    GB b{};
    GJOB(b, 0, B0, 256, pair0, nullptr, dinvP, TL0, 256, 512, 0, 2);
    hipLaunchKernelGGL(gemm_batch, dim3(GMAX, 1), blk, 0, stream, b);
  }

  // ---- S1: stage{4d -> Bd, 4p -> Bp, gs1 -> Bh} + ln_elu{B0 -> B4e} ----
  {
    SB s{};
    SJOB(s, 0, rowptrD, colD, dinvD, TLd, 512, dd1_b, dr1_b,
         rowptrTD, colTD, icD, B4a, nullptr, nullptr, Bd, 1024, DN, 1);
    SJOB(s, 1, rowptrP, colP, dinvP, TLp, 512, pp1_b, pr1_b,
         rowptrTP, colTP, icP, B4b, nullptr, nullptr, Bp, 1024, PN, 1);
    SJOB(s, 2, rowptrP, colP, dinvP, TL0, 512, gs1_gcn_b, nullptr,
         nullptr, nullptr, nullptr, nullptr, gs1_ln_w, gs1_ln_b, Bh, 256, PN, 1);
    LJOB(s, 3, B0, 256, B4e, 256, PN);
    hipLaunchKernelGGL(stage_batch, dim3(SROWS, 4), blk, 0, stream, s);
  }

  // ---- G3: 4 GEMMs (P3-t, P5-t, P5-proj, xfp) ----
  {
    GB b{};
    GJOB(b, 0, Bh,  256,  pair1, nullptr, dinvP,   TLd,      256, 512,  0, 2);
    GJOB(b, 1, Bp,  1024, pair4, nullptr, dinvP,   TLp,      256, 512,  0, 2);
    GJOB(b, 2, Bd,  1024, Wtd2,  td2_b,   nullptr, B4a,      256, 256,  0, 1);
    GJOB(b, 3, B4e, 256,  Wsfc,  nullptr, nullptr, PK + 256, 256, 1024, 2, 1);
    hipLaunchKernelGGL(gemm_batch, dim3(GMAX, 4), blk, 0, stream, b);
  }

  // ---- S2: stage{gs2 -> PK slot0, P5 -> PK slot2} ----
  {
    SB s{};
    SJOB(s, 0, rowptrP, colP, dinvP, TLd, 512, gs2_gcn_b, nullptr,
         nullptr, nullptr, nullptr, nullptr, gs2_ln_w, gs2_ln_b, PK + 0, 1024, PN, 0);
    SJOB(s, 1, rowptrP, colP, dinvP, TLp, 512, pp2_b, pr2_b,
         rowptrTP, colTP, icP, B4a, nullptr, nullptr, PK + 512, 1024, PN, 0);
    hipLaunchKernelGGL(stage_batch, dim3(SROWS, 2), blk, 0, stream, s);
  }

  // ---- pair epilogue ----
  hipLaunchKernelGGL(pair_kernel, dim3((NPAIRN + 7) / 8), blk, 0, stream,
                     PK, idx1, idx2, wR, wI, outp, NPAIRN);
}

// Round 18
// 639.827 us; speedup vs baseline: 1.1651x; 1.1008x over previous
//
#include <hip/hip_runtime.h>
#include <hip/hip_bf16.h>
#include <math.h>

#define PN 20000
#define DN 20000
#define SEQK 1024
#define EPPI 640000
#define EDDI 640000
#define EDTI 400000
#define NPAIRN 100000
#define RPB 128            // rows per bucket
#define NBUCK 157          // ceil(20000/128)
#define CH 4096            // edges per sort block
#define NBLKMAX 157        // ceil(640000/4096)
#define RBX 40             // row-blocks per XCD = ceil(313/8)
#define KT 256             // K-chunk staged in LDS
#define XPAD 264           // padded LDS row stride (bf16)

typedef float4 f4;
using bf16x8 = __attribute__((ext_vector_type(8))) __bf16;
using bf16x4 = __attribute__((ext_vector_type(4))) __bf16;
using f32x4v = __attribute__((ext_vector_type(4))) float;

__device__ __forceinline__ f4 ld4(const float* p) { return *reinterpret_cast<const f4*>(p); }
__device__ __forceinline__ f4 ldb4(const __bf16* p) {
  bf16x4 v = *reinterpret_cast<const bf16x4*>(p);
  return make_float4((float)v[0], (float)v[1], (float)v[2], (float)v[3]);
}
__device__ __forceinline__ void stb4(__bf16* p, f4 v) {
  bf16x4 o;
  o[0] = (__bf16)v.x; o[1] = (__bf16)v.y; o[2] = (__bf16)v.z; o[3] = (__bf16)v.w;
  *reinterpret_cast<bf16x4*>(p) = o;
}
__device__ __forceinline__ void acc4(f4& a, f4 b) { a.x+=b.x; a.y+=b.y; a.z+=b.z; a.w+=b.w; }
__device__ __forceinline__ void acc4s(f4& a, f4 b, float s) { a.x+=s*b.x; a.y+=s*b.y; a.z+=s*b.z; a.w+=s*b.w; }

__device__ __forceinline__ void wave_ln(f4& x) {
  float s  = x.x + x.y + x.z + x.w;
  float ss = x.x*x.x + x.y*x.y + x.z*x.z + x.w*x.w;
#pragma unroll
  for (int o = 32; o; o >>= 1) { s += __shfl_xor(s, o, 64); ss += __shfl_xor(ss, o, 64); }
  float m = s * (1.f/256.f);
  float v = ss * (1.f/256.f) - m*m;
  float r = rsqrtf(v + 1e-5f);
  x.x = (x.x-m)*r; x.y = (x.y-m)*r; x.z = (x.z-m)*r; x.w = (x.w-m)*r;
}

// LN over 256 feats held as 8 floats/lane across a 32-lane half-wave.
__device__ __forceinline__ void ln8(float* v) {
  float s = 0.f, ss = 0.f;
#pragma unroll
  for (int i = 0; i < 8; ++i) { s += v[i]; ss += v[i]*v[i]; }
#pragma unroll
  for (int o = 16; o; o >>= 1) { s += __shfl_xor(s, o, 64); ss += __shfl_xor(ss, o, 64); }
  float m = s * (1.f/256.f);
  float var = ss * (1.f/256.f) - m*m;
  float r = rsqrtf(var + 1e-5f);
#pragma unroll
  for (int i = 0; i < 8; ++i) v[i] = (v[i]-m)*r;
}

// ---------------- fp32 -> bf16 converter (weights + embeddings, 19 jobs) ----------------
struct CPack { const float* src[19]; __bf16* dst[19]; int n[19]; };
__global__ __launch_bounds__(256) void convert_all(CPack p) {
  const int wi = blockIdx.y;
  const int n = p.n[wi];
  const float* s = p.src[wi];
  __bf16* d = p.dst[wi];
  for (int i = (blockIdx.x * 256 + threadIdx.x) * 4; i < n; i += gridDim.x * 256 * 4) {
    f4 v = ld4(s + i);
    stb4(d + i, v);
  }
}

// ---------------- contention-free two-level counting-sort CSR build ----------------
struct GPack {
  const int* src[4]; const int* dst[4]; int nE[4];
  int* col[4]; int* rowptr[4]; float* outdeg[4];  // dinvP,dinvD,icD,icP
  unsigned* stg[4];
  int* bh;      // [4][NBUCK][NBLKMAX]
  int* bbase;   // [4][NBUCK+1]
};

__global__ __launch_bounds__(256) void sort_hist(GPack g) {
  __shared__ int h[NBUCK];
  const int gi = blockIdx.y, blk = blockIdx.x;
  const int t = threadIdx.x;
  for (int i = t; i < NBUCK; i += 256) h[i] = 0;
  __syncthreads();
  const int base = blk * CH, nE = g.nE[gi];
  const int* dst = g.dst[gi];
#pragma unroll
  for (int i = 0; i < CH / 256; ++i) {
    int e = base + i * 256 + t;
    if (e < nE) atomicAdd(&h[dst[e] >> 7], 1);
  }
  __syncthreads();
  int* bh = g.bh + (size_t)gi * NBUCK * NBLKMAX;
  for (int i = t; i < NBUCK; i += 256) bh[i * NBLKMAX + blk] = h[i];
}

__global__ __launch_bounds__(1024) void sort_scan(GPack g) {
  __shared__ int sums[1024];
  const int gi = blockIdx.y;
  int* bh = g.bh + (size_t)gi * NBUCK * NBLKMAX;
  int* bbase = g.bbase + gi * (NBUCK + 1);
  const int L = NBUCK * NBLKMAX;
  const int t = threadIdx.x;
  const int chunk = (L + 1023) / 1024;
  const int b = t * chunk;
  const int e = min(b + chunk, L);
  int s = 0;
  for (int i = b; i < e; ++i) s += bh[i];
  sums[t] = s;
  __syncthreads();
  for (int o = 1; o < 1024; o <<= 1) {
    int u = (t >= o) ? sums[t - o] : 0;
    __syncthreads();
    sums[t] += u;
    __syncthreads();
  }
  int run = sums[t] - s;
  for (int i = b; i < e; ++i) {
    if (i % NBLKMAX == 0) bbase[i / NBLKMAX] = run;
    int old = bh[i];
    bh[i] = run;
    run += old;
  }
  if (t == 0) bbase[NBUCK] = g.nE[gi];
}

__global__ __launch_bounds__(256) void sort_scatter(GPack g) {
  __shared__ int cur[NBUCK];
  const int gi = blockIdx.y, blk = blockIdx.x;
  const int t = threadIdx.x;
  const int* bh = g.bh + (size_t)gi * NBUCK * NBLKMAX;
  for (int i = t; i < NBUCK; i += 256) cur[i] = bh[i * NBLKMAX + blk];
  __syncthreads();
  const int base = blk * CH, nE = g.nE[gi];
  const int* src = g.src[gi];
  const int* dst = g.dst[gi];
  unsigned* stg = g.stg[gi];
#pragma unroll
  for (int i = 0; i < CH / 256; ++i) {
    int e = base + i * 256 + t;
    if (e < nE) {
      int d = dst[e];
      int bkt = d >> 7;
      int pos = atomicAdd(&cur[bkt], 1);
      stg[pos] = ((unsigned)src[e] << 7) | (unsigned)(d & 127);
    }
  }
}

__global__ __launch_bounds__(256) void bucket_csr(GPack g) {
  const int gi = blockIdx.y;
  const int b = blockIdx.x;
  const int base = g.bbase[gi * (NBUCK + 1) + b];
  const int cnt  = g.bbase[gi * (NBUCK + 1) + b + 1] - base;
  __shared__ int h[RPB], sc[RPB];
  const int t = threadIdx.x;
  if (t < RPB) h[t] = 0;
  __syncthreads();
  const unsigned* st = g.stg[gi] + base;
  const int row0 = b * RPB;
  for (int i = t; i < cnt; i += 256) atomicAdd(&h[st[i] & 127u], 1);
  __syncthreads();
  if (t == 0) { int run = 0; for (int r = 0; r < RPB; ++r) { sc[r] = run; run += h[r]; } }
  __syncthreads();
  const int rows = min(RPB, PN - row0);
  if (t < rows) {
    g.rowptr[gi][row0 + t] = base + sc[t];
    float c = (float)h[t];
    g.outdeg[gi][row0 + t] = (gi < 2) ? rsqrtf(c + 1.f) : (1.f / fmaxf(c, 1.f));
  }
  if (b == 0 && t == 0) g.rowptr[gi][PN] = g.nE[gi];
  __syncthreads();
  if (t < RPB) h[t] = sc[t];
  __syncthreads();
  for (int i = t; i < cnt; i += 256) {
    unsigned v = st[i];
    int pos = atomicAdd(&h[v & 127u], 1);
    g.col[gi][base + pos] = (int)(v >> 7);
  }
}

// ---------------- batched GEMM v4: LDS-staged X tile; wave computes 64x64 ----------------
struct GB {
  const __bf16* X[6]; int lda[6];
  const __bf16* Wt[6]; const float* bias[6]; const float* scale[6];
  __bf16* out[6]; int K[6]; int ostride[6]; int act[6]; int ncol[6];  // ncol = N/256
};

__global__ __launch_bounds__(256) void gemm_batch(GB gb) {
  __shared__ __bf16 XS[64][XPAD];
  const int y = blockIdx.y;
  const int colchunk = gb.ncol[y];
  const int bid = blockIdx.x;
  if (bid >= 8 * RBX * colchunk) return;
  const int xcd = bid & 7;
  const int j = bid >> 3;
  const int row_blk = xcd * RBX + j / colchunk;
  const int cc = j % colchunk;
  const int M = PN;
  if (row_blk * 64 >= M) return;

  const __bf16* X  = gb.X[y];
  const __bf16* Wt = gb.Wt[y];
  const float* bias = gb.bias[y];
  const float* scale = gb.scale[y];
  __bf16* outb = gb.out[y];
  const int lda = gb.lda[y];
  const int K = gb.K[y];
  const int ostride = gb.ostride[y];
  const int act = gb.act[y];

  const int tid = threadIdx.x;
  const int lane = tid & 63;
  const int w = tid >> 6;
  const int r0 = row_blk * 64;
  const int c0 = cc * 256 + w * 64;
  const int l15 = lane & 15;
  const int lk = (lane >> 4) * 8;

  f32x4v acc[4][4];
#pragma unroll
  for (int m = 0; m < 4; ++m)
#pragma unroll
    for (int n = 0; n < 4; ++n) { acc[m][n][0]=0.f; acc[m][n][1]=0.f; acc[m][n][2]=0.f; acc[m][n][3]=0.f; }

  const __bf16* wp[4];
#pragma unroll
  for (int n = 0; n < 4; ++n) {
    wp[n] = Wt + (size_t)(c0 + n * 16 + l15) * K + lk;
  }

  const int srow = tid >> 5;   // 0..7
  const int sseg = tid & 31;   // 0..31 (16B segments per 512B row-chunk)

  for (int kc = 0; kc < K; kc += KT) {
    if (kc) __syncthreads();   // protect XS reuse across chunks
    // stage X[r0..r0+63][kc..kc+KT) -> XS (coalesced 512B per row)
#pragma unroll
    for (int it = 0; it < 8; ++it) {
      int rl = it * 8 + srow;
      int rg = min(r0 + rl, M - 1);
      bf16x8 v = *reinterpret_cast<const bf16x8*>(X + (size_t)rg * lda + kc + sseg * 8);
      *reinterpret_cast<bf16x8*>(&XS[rl][sseg * 8]) = v;
    }
    __syncthreads();

#pragma unroll 2
    for (int k0 = 0; k0 < KT; k0 += 32) {
      bf16x8 a[4], b[4];
#pragma unroll
      for (int m = 0; m < 4; ++m)
        a[m] = *reinterpret_cast<const bf16x8*>(&XS[m * 16 + l15][k0 + lk]);
#pragma unroll
      for (int n = 0; n < 4; ++n)
        b[n] = *reinterpret_cast<const bf16x8*>(wp[n] + kc + k0);
#pragma unroll
      for (int m = 0; m < 4; ++m)
#pragma unroll
        for (int n = 0; n < 4; ++n)
          acc[m][n] = __builtin_amdgcn_mfma_f32_16x16x32_bf16(a[m], b[n], acc[m][n], 0, 0, 0);
    }
  }

  const int rq = (lane >> 4) * 4;
#pragma unroll
  for (int m = 0; m < 4; ++m) {
#pragma unroll
    for (int i = 0; i < 4; ++i) {
      int row = r0 + m * 16 + rq + i;
      if (row >= M) continue;
#pragma unroll
      for (int n = 0; n < 4; ++n) {
        int col = c0 + n * 16 + l15;
        float v = acc[m][n][i];
        if (bias) v += bias[col];
        if (act == 1) v = fmaxf(v, 0.f);
        else if (act == 2) v = v > 0.f ? v : (expf(v) - 1.f);
        if (scale && col < 256) v *= scale[row];
        outb[(size_t)row * ostride + col] = (__bf16)v;
      }
    }
  }
}

// ---------------- batched fused GCN stage (mode 0) / ln_elu (mode 1) ----------------
struct SB {
  const int* rpG[4]; const int* clG[4]; const float* dinv[4];
  const __bf16* T[4]; int tstr[4];
  const float* gbias[4]; const float* linb[4];
  const int* rpS[4]; const int* clS[4]; const float* ic[4]; const __bf16* Pt[4];
  const float* lw[4]; const float* lb[4];
  __bf16* out[4]; int ostr[4]; int n[4]; int act[4]; int mode[4];
};

__global__ __launch_bounds__(256) void stage_batch(SB sb) {
  const int y = blockIdx.y;
  int row = (blockIdx.x * blockDim.x + threadIdx.x) >> 6;
  if (row >= sb.n[y]) return;
  int lane = threadIdx.x & 63;
  int o = lane * 4;
  const __bf16* T = sb.T[y];
  const int tstr = sb.tstr[y];
  __bf16* out = sb.out[y];
  const int ostr = sb.ostr[y];

  if (sb.mode[y] == 1) {   // fp = elu(LN(T_row))
    f4 x = ldb4(T + (size_t)row * tstr + o);
    wave_ln(x);
    x.x = x.x > 0.f ? x.x : expf(x.x)-1.f;
    x.y = x.y > 0.f ? x.y : expf(x.y)-1.f;
    x.z = x.z > 0.f ? x.z : expf(x.z)-1.f;
    x.w = x.w > 0.f ? x.w : expf(x.w)-1.f;
    stb4(out + (size_t)row * ostr + o, x);
    return;
  }

  const int* rpG = sb.rpG[y];
  const int* clG = sb.clG[y];
  const float* dinv = sb.dinv[y];
  float dd = dinv[row];

  // T is pre-scaled by dinv (t' rows); gacc = self + neighbors, x = dd*gacc.
  f4 gacc = ldb4(T + (size_t)row * tstr + o);

  int beg = rpG[row], end = rpG[row + 1];
  int j = beg;
  for (; j + 7 < end; j += 8) {
    int s[8];
    f4 tv[8];
#pragma unroll
    for (int q = 0; q < 8; ++q) s[q] = clG[j + q];
#pragma unroll
    for (int q = 0; q < 8; ++q) tv[q] = ldb4(T + (size_t)s[q] * tstr + o);
#pragma unroll
    for (int q = 0; q < 8; ++q) acc4(gacc, tv[q]);
  }
  for (; j < end; ++j) {
    acc4(gacc, ldb4(T + (size_t)clG[j] * tstr + o));
  }

  f4 x = make_float4(0.f, 0.f, 0.f, 0.f);
  acc4s(x, gacc, dd);

  if (sb.gbias[y]) acc4(x, ld4(sb.gbias[y] + o));
  if (sb.linb[y])  acc4(x, ld4(sb.linb[y] + o));
  acc4(x, ldb4(T + (size_t)row * tstr + 256 + o));   // lin half of TL

  if (sb.rpS[y]) {
    const int* rpS = sb.rpS[y];
    const int* clS = sb.clS[y];
    const __bf16* Pt = sb.Pt[y];
    f4 s4 = make_float4(0.f, 0.f, 0.f, 0.f);
    int sbg = rpS[row], se = rpS[row + 1];
    int k = sbg;
    for (; k + 7 < se; k += 8) {
      int s[8];
      f4 tv[8];
#pragma unroll
      for (int q = 0; q < 8; ++q) s[q] = clS[k + q];
#pragma unroll
      for (int q = 0; q < 8; ++q) tv[q] = ldb4(Pt + (size_t)s[q] * 256 + o);
#pragma unroll
      for (int q = 0; q < 8; ++q) acc4(s4, tv[q]);
    }
    for (; k < se; ++k) acc4(s4, ldb4(Pt + (size_t)clS[k] * 256 + o));
    acc4s(x, s4, sb.ic[y][row]);
  }

  wave_ln(x);
  if (sb.lw[y]) {
    f4 w = ld4(sb.lw[y] + o), b = ld4(sb.lb[y] + o);
    x.x = x.x*w.x + b.x; x.y = x.y*w.y + b.y; x.z = x.z*w.z + b.z; x.w = x.w*w.w + b.w;
  }
  if (sb.act[y] == 1) {
    x.x = fmaxf(x.x, 0.f); x.y = fmaxf(x.y, 0.f); x.z = fmaxf(x.z, 0.f); x.w = fmaxf(x.w, 0.f);
  }
  stb4(out + (size_t)row * ostr + o, x);
}

// ---------------- pair epilogue: one pair per 32-lane half-wave ----------------
__global__ __launch_bounds__(256) void pair_kernel(
    const __bf16* __restrict__ PK,
    const int* __restrict__ idx1, const int* __restrict__ idx2,
    const float* __restrict__ wR, const float* __restrict__ wI,
    float* __restrict__ out, int npair)
{
  int pid = (blockIdx.x * 256 + threadIdx.x) >> 5;
  if (pid >= npair) return;
  int l = threadIdx.x & 31;
  int f = l * 8;
  const __bf16* r1 = PK + (size_t)idx1[pid] * 1024;
  const __bf16* r2 = PK + (size_t)idx2[pid] * 1024;

  bf16x8 a0 = *reinterpret_cast<const bf16x8*>(r1 + f);
  bf16x8 a1 = *reinterpret_cast<const bf16x8*>(r1 + 256 + f);
  bf16x8 a2 = *reinterpret_cast<const bf16x8*>(r1 + 512 + f);
  bf16x8 a3 = *reinterpret_cast<const bf16x8*>(r1 + 768 + f);
  bf16x8 b0 = *reinterpret_cast<const bf16x8*>(r2 + f);
  bf16x8 b1 = *reinterpret_cast<const bf16x8*>(r2 + 256 + f);
  bf16x8 b2 = *reinterpret_cast<const bf16x8*>(r2 + 512 + f);
  bf16x8 b3 = *reinterpret_cast<const bf16x8*>(r2 + 768 + f);

  float R1[8], I1[8], R2[8], I2[8];
#pragma unroll
  for (int i = 0; i < 8; ++i) {
    R1[i] = (float)a0[i] + (float)b1[i];
    I1[i] = (float)a2[i] + (float)b3[i];
    R2[i] = (float)a3[i] + (float)b2[i];
    I2[i] = (float)a1[i] + (float)b0[i];
  }
  ln8(R1); ln8(I1); ln8(R2); ln8(I2);

  float R[8], I[8];
#pragma unroll
  for (int i = 0; i < 8; ++i) {
    R[i] = R1[i]*R2[i] - I1[i]*I2[i];
    I[i] = R1[i]*I2[i] + I1[i]*R2[i];
  }
  ln8(R); ln8(I);

  f4 wr0 = ld4(wR + f), wr1 = ld4(wR + f + 4);
  f4 wi0 = ld4(wI + f), wi1 = ld4(wI + f + 4);
  float wrv[8] = {wr0.x,wr0.y,wr0.z,wr0.w, wr1.x,wr1.y,wr1.z,wr1.w};
  float wiv[8] = {wi0.x,wi0.y,wi0.z,wi0.w, wi1.x,wi1.y,wi1.z,wi1.w};
  float t = 0.f;
#pragma unroll
  for (int i = 0; i < 8; ++i) t += R[i]*(wrv[i]-wiv[i]) + I[i]*(wrv[i]+wiv[i]);
#pragma unroll
  for (int o = 16; o; o >>= 1) t += __shfl_xor(t, o, 64);
  if (l == 0) out[pid] = 1.f / (1.f + expf(-t));
}

extern "C" void kernel_launch(void* const* d_in, const int* in_sizes, int n_in,
                              void* d_out, int out_size, void* d_ws, size_t ws_size,
                              hipStream_t stream) {
  (void)in_sizes; (void)n_in; (void)out_size; (void)ws_size;
  const float* seq        = (const float*)d_in[0];
  const int*   ppi        = (const int*)d_in[1];
  const int*   ddi        = (const int*)d_in[2];
  const int*   dti        = (const int*)d_in[3];
  const int*   idx1       = (const int*)d_in[4];
  const int*   idx2       = (const int*)d_in[5];
  const float* seq_init_W = (const float*)d_in[6];
  const float* gs1_gcn_W  = (const float*)d_in[7];
  const float* gs1_gcn_b  = (const float*)d_in[8];
  const float* gs1_lin_W  = (const float*)d_in[9];
  const float* gs1_ln_w   = (const float*)d_in[10];
  const float* gs1_ln_b   = (const float*)d_in[11];
  const float* gs2_gcn_W  = (const float*)d_in[12];
  const float* gs2_gcn_b  = (const float*)d_in[13];
  const float* gs2_lin_W  = (const float*)d_in[14];
  const float* gs2_ln_w   = (const float*)d_in[15];
  const float* gs2_ln_b   = (const float*)d_in[16];
  const float* drug_emb   = (const float*)d_in[17];
  const float* prot_emb   = (const float*)d_in[18];
  const float* pp1_W = (const float*)d_in[19]; const float* pp1_b = (const float*)d_in[20];
  const float* td1_W = (const float*)d_in[21]; const float* td1_b = (const float*)d_in[22];
  const float* pr1_W = (const float*)d_in[23]; const float* pr1_b = (const float*)d_in[24];
  const float* dd1_W = (const float*)d_in[25]; const float* dd1_b = (const float*)d_in[26];
  const float* dt1_W = (const float*)d_in[27]; const float* dt1_b = (const float*)d_in[28];
  const float* dr1_W = (const float*)d_in[29]; const float* dr1_b = (const float*)d_in[30];
  const float* pp2_W = (const float*)d_in[31]; const float* pp2_b = (const float*)d_in[32];
  const float* td2_W = (const float*)d_in[33]; const float* td2_b = (const float*)d_in[34];
  const float* pr2_W = (const float*)d_in[35]; const float* pr2_b = (const float*)d_in[36];
  const float* seq_fc_W  = (const float*)d_in[43];
  const float* skip_fc_W = (const float*)d_in[44];
  const float* wR = (const float*)d_in[45];
  const float* wI = (const float*)d_in[46];
  float* outp = (float*)d_out;

  // ---------------- workspace layout ----------------
  char* base = (char*)d_ws;
  unsigned* stgP  = (unsigned*)base;                 // EPPI
  unsigned* stgD  = stgP + EPPI;
  unsigned* stgTD = stgD + EDDI;
  unsigned* stgTP = stgTD + EDTI;
  int* colP  = (int*)(stgTP + EDTI);
  int* colD  = colP + EPPI;
  int* colTD = colD + EDDI;
  int* colTP = colTD + EDTI;
  int* rowptrP  = colTP + EDTI;
  int* rowptrD  = rowptrP + PN + 1;
  int* rowptrTD = rowptrD + PN + 1;
  int* rowptrTP = rowptrTD + PN + 1;
  float* dinvP = (float*)(rowptrTP + PN + 1);
  float* dinvD = dinvP + PN;
  float* icD   = dinvD + PN;
  float* icP   = icD + PN;
  int* bh    = (int*)(icP + PN);                     // 4*NBUCK*NBLKMAX
  int* bbase = bh + 4 * NBUCK * NBLKMAX;             // 4*(NBUCK+1)

  unsigned long long waddr = (unsigned long long)(bbase + 4 * (NBUCK + 1));
  waddr = (waddr + 63ULL) & ~63ULL;
  __bf16* wb = (__bf16*)waddr;
  __bf16* Wseq  = wb;                           // [256,1024]
  __bf16* pair0 = Wseq + 256*1024;              // each pair [512,256]
  __bf16* pair1 = pair0 + 512*256;
  __bf16* pair2 = pair1 + 512*256;
  __bf16* pair3 = pair2 + 512*256;
  __bf16* pair4 = pair3 + 512*256;
  __bf16* sing  = pair4 + 512*256;
  __bf16* Wdt1  = sing;
  __bf16* Wtd1  = sing + 65536;
  __bf16* Wtd2  = sing + 2*65536;
  __bf16* Wsfc  = sing + 3*65536;
  __bf16* Wskp  = sing + 4*65536;
  const size_t NB = (size_t)PN * 256;
  __bf16* Ed    = sing + 5*65536;               // [20000,256]
  __bf16* Ep    = Ed + NB;
  __bf16* TL0   = Ep + NB;                      // [20000,512]
  __bf16* TLd   = TL0 + (size_t)PN*512;         // [20000,512]
  __bf16* TLp   = TLd + (size_t)PN*512;         // [20000,512]
  __bf16* B0    = TLp + (size_t)PN*512;         // x_seq
  __bf16* Bh    = B0 + NB;                      // h
  __bf16* B4a   = Bh + NB;                      // proj_p (4d) -> P5 proj
  __bf16* B4b   = B4a + NB;                     // proj_d (4p)
  __bf16* B4e   = B4b + NB;                     // fp
  __bf16* PK    = B4e + NB;                     // [20000][1024]: x1 | xfp | p2 | xskip
  __bf16* Eseq  = PK;                           // alias, dead after G1
  __bf16* Bd    = PK + 0;                       // d, stride 1024 (slot0)
  __bf16* Bp    = PK + 512;                     // p, stride 1024 (slot2)

  const dim3 blk(256);
  const dim3 sgrid(NBLKMAX, 4);
  const dim3 bgrid(NBUCK, 4);
  const int SROWS = (PN + 3) / 4;      // 5000 blocks for stage jobs
  const int GMAX  = 8 * RBX * 2;       // 640 blocks for colchunk<=2 gemm

  // ---- converts (1 launch, 19 jobs) ----
  {
    CPack p;
    const float* srcs[19] = { seq_init_W, gs1_gcn_W, gs1_lin_W, gs2_gcn_W, gs2_lin_W,
                              dd1_W, dr1_W, pp1_W, pr1_W, pp2_W, pr2_W,
                              dt1_W, td1_W, td2_W, seq_fc_W, skip_fc_W,
                              seq, drug_emb, prot_emb };
    __bf16* dsts[19] = { Wseq, pair0, pair0 + 65536, pair1, pair1 + 65536,
                         pair2, pair2 + 65536, pair3, pair3 + 65536, pair4, pair4 + 65536,
                         Wdt1, Wtd1, Wtd2, Wsfc, Wskp,
                         Eseq, Ed, Ep };
    for (int i = 0; i < 19; ++i) {
      p.src[i] = srcs[i]; p.dst[i] = dsts[i];
      p.n[i] = (i == 0) ? 256*1024 : (i == 16) ? PN*SEQK : (i >= 17) ? PN*256 : 256*256;
    }
    hipLaunchKernelGGL(convert_all, dim3(2048, 19), blk, 0, stream, p);
  }

  // ---- counting-sort CSR build ----
  GPack g;
  g.src[0] = ppi;        g.dst[0] = ppi + EPPI; g.nE[0] = EPPI;
  g.src[1] = ddi;        g.dst[1] = ddi + EDDI; g.nE[1] = EDDI;
  g.src[2] = dti + EDTI; g.dst[2] = dti;        g.nE[2] = EDTI;
  g.src[3] = dti;        g.dst[3] = dti + EDTI; g.nE[3] = EDTI;
  g.col[0] = colP;  g.col[1] = colD;  g.col[2] = colTD;  g.col[3] = colTP;
  g.rowptr[0] = rowptrP; g.rowptr[1] = rowptrD; g.rowptr[2] = rowptrTD; g.rowptr[3] = rowptrTP;
  g.outdeg[0] = dinvP; g.outdeg[1] = dinvD; g.outdeg[2] = icD; g.outdeg[3] = icP;
  g.stg[0] = stgP; g.stg[1] = stgD; g.stg[2] = stgTD; g.stg[3] = stgTP;
  g.bh = bh; g.bbase = bbase;

  hipLaunchKernelGGL(sort_hist,    sgrid, blk, 0, stream, g);
  hipLaunchKernelGGL(sort_scan,    dim3(1, 4), dim3(1024), 0, stream, g);
  hipLaunchKernelGGL(sort_scatter, sgrid, blk, 0, stream, g);
  hipLaunchKernelGGL(bucket_csr,   bgrid, blk, 0, stream, g);

  auto GJOB = [&](GB& b, int i, const __bf16* X, int lda, const __bf16* Wt, const float* bias,
                  const float* scale, __bf16* out, int K, int ostr, int act, int colchunk) {
    b.X[i]=X; b.lda[i]=lda; b.Wt[i]=Wt; b.bias[i]=bias; b.scale[i]=scale;
    b.out[i]=out; b.K[i]=K; b.ostride[i]=ostr; b.act[i]=act; b.ncol[i]=colchunk;
  };
  auto SJOB = [&](SB& s, int i, const int* rpG, const int* clG, const float* dv,
                  const __bf16* T, int tstr, const float* gb, const float* lnb,
                  const int* rpS, const int* clS, const float* ic, const __bf16* Pt,
                  const float* lw, const float* lb, __bf16* out, int ostr, int n, int act) {
    s.mode[i]=0; s.rpG[i]=rpG; s.clG[i]=clG; s.dinv[i]=dv; s.T[i]=T; s.tstr[i]=tstr;
    s.gbias[i]=gb; s.linb[i]=lnb; s.rpS[i]=rpS; s.clS[i]=clS; s.ic[i]=ic; s.Pt[i]=Pt;
    s.lw[i]=lw; s.lb[i]=lb; s.out[i]=out; s.ostr[i]=ostr; s.n[i]=n; s.act[i]=act;
  };
  auto LJOB = [&](SB& s, int i, const __bf16* T, int tstr, __bf16* out, int ostr, int n) {
    s.mode[i]=1; s.T[i]=T; s.tstr[i]=tstr; s.out[i]=out; s.ostr[i]=ostr; s.n[i]=n;
  };

  // ---- G1: 6 GEMMs (P1, 4d-t, 4d-proj, 4p-t, 4p-proj, xskip) ----
  {
    GB b{};
    GJOB(b, 0, Eseq, 1024, Wseq,  nullptr, nullptr, B0,       1024, 256,  1, 1);
    GJOB(b, 1, Ed,   256,  pair2, nullptr, dinvD,   TLd,      256,  512,  0, 2);
    GJOB(b, 2, Ep,   256,  Wdt1,  dt1_b,   nullptr, B4a,      256,  256,  0, 1);
    GJOB(b, 3, Ep,   256,  pair3, nullptr, dinvP,   TLp,      256,  512,  0, 2);
    GJOB(b, 4, Ed,   256,  Wtd1,  td1_b,   nullptr, B4b,      256,  256,  0, 1);
    GJOB(b, 5, Ep,   256,  Wskp,  nullptr, nullptr, PK + 768, 256,  1024, 0, 1);
    hipLaunchKernelGGL(gemm_batch, dim3(GMAX, 6), blk, 0, stream, b);
  }

  // ---- G2: 1 GEMM (P2-t) ----
  {
    GB b{};
    GJOB(b, 0, B0, 256, pair0, nullptr, dinvP, TL0, 256, 512, 0, 2);
    hipLaunchKernelGGL(gemm_batch, dim3(GMAX, 1), blk, 0, stream, b);
  }

  // ---- S1: stage{4d -> Bd, 4p -> Bp, gs1 -> Bh} + ln_elu{B0 -> B4e} ----
  {
    SB s{};
    SJOB(s, 0, rowptrD, colD, dinvD, TLd, 512, dd1_b, dr1_b,
         rowptrTD, colTD, icD, B4a, nullptr, nullptr, Bd, 1024, DN, 1);
    SJOB(s, 1, rowptrP, colP, dinvP, TLp, 512, pp1_b, pr1_b,
         rowptrTP, colTP, icP, B4b, nullptr, nullptr, Bp, 1024, PN, 1);
    SJOB(s, 2, rowptrP, colP, dinvP, TL0, 512, gs1_gcn_b, nullptr,
         nullptr, nullptr, nullptr, nullptr, gs1_ln_w, gs1_ln_b, Bh, 256, PN, 1);
    LJOB(s, 3, B0, 256, B4e, 256, PN);
    hipLaunchKernelGGL(stage_batch, dim3(SROWS, 4), blk, 0, stream, s);
  }

  // ---- G3: 4 GEMMs (P3-t, P5-t, P5-proj, xfp) ----
  {
    GB b{};
    GJOB(b, 0, Bh,  256,  pair1, nullptr, dinvP,   TLd,      256, 512,  0, 2);
    GJOB(b, 1, Bp,  1024, pair4, nullptr, dinvP,   TLp,      256, 512,  0, 2);
    GJOB(b, 2, Bd,  1024, Wtd2,  td2_b,   nullptr, B4a,      256, 256,  0, 1);
    GJOB(b, 3, B4e, 256,  Wsfc,  nullptr, nullptr, PK + 256, 256, 1024, 2, 1);
    hipLaunchKernelGGL(gemm_batch, dim3(GMAX, 4), blk, 0, stream, b);
  }

  // ---- S2: stage{gs2 -> PK slot0, P5 -> PK slot2} ----
  {
    SB s{};
    SJOB(s, 0, rowptrP, colP, dinvP, TLd, 512, gs2_gcn_b, nullptr,
         nullptr, nullptr, nullptr, nullptr, gs2_ln_w, gs2_ln_b, PK + 0, 1024, PN, 0);
    SJOB(s, 1, rowptrP, colP, dinvP, TLp, 512, pp2_b, pr2_b,
         rowptrTP, colTP, icP, B4a, nullptr, nullptr, PK + 512, 1024, PN, 0);
    hipLaunchKernelGGL(stage_batch, dim3(SROWS, 2), blk, 0, stream, s);
  }

  // ---- pair epilogue ----
  hipLaunchKernelGGL(pair_kernel, dim3((NPAIRN + 7) / 8), blk, 0, stream,
                     PK, idx1, idx2, wR, wI, outp, NPAIRN);
}

// Round 19
// 627.561 us; speedup vs baseline: 1.1879x; 1.0195x over previous
//
#include <hip/hip_runtime.h>
#include <hip/hip_bf16.h>
#include <math.h>

#define PN 20000
#define DN 20000
#define SEQK 1024
#define EPPI 640000
#define EDDI 640000
#define EDTI 400000
#define NPAIRN 100000
#define RPB 128            // rows per bucket
#define NBUCK 157          // ceil(20000/128)
#define CH 4096            // edges per sort block
#define NBLKMAX 157        // ceil(640000/4096)
#define RBX 40             // row-blocks per XCD = ceil(313/8)
#define KT 256             // K-chunk staged in LDS
#define XPAD 264           // padded LDS row stride (bf16)

typedef float4 f4;
using bf16x8 = __attribute__((ext_vector_type(8))) __bf16;
using bf16x4 = __attribute__((ext_vector_type(4))) __bf16;
using f32x4v = __attribute__((ext_vector_type(4))) float;

__device__ __forceinline__ f4 ld4(const float* p) { return *reinterpret_cast<const f4*>(p); }
__device__ __forceinline__ f4 ldb4(const __bf16* p) {
  bf16x4 v = *reinterpret_cast<const bf16x4*>(p);
  return make_float4((float)v[0], (float)v[1], (float)v[2], (float)v[3]);
}
__device__ __forceinline__ void stb4(__bf16* p, f4 v) {
  bf16x4 o;
  o[0] = (__bf16)v.x; o[1] = (__bf16)v.y; o[2] = (__bf16)v.z; o[3] = (__bf16)v.w;
  *reinterpret_cast<bf16x4*>(p) = o;
}
__device__ __forceinline__ void acc4(f4& a, f4 b) { a.x+=b.x; a.y+=b.y; a.z+=b.z; a.w+=b.w; }
__device__ __forceinline__ void acc4s(f4& a, f4 b, float s) { a.x+=s*b.x; a.y+=s*b.y; a.z+=s*b.z; a.w+=s*b.w; }

// LN over 256 feats held as 8 floats/lane across a 32-lane half-wave.
__device__ __forceinline__ void ln8(float* v) {
  float s = 0.f, ss = 0.f;
#pragma unroll
  for (int i = 0; i < 8; ++i) { s += v[i]; ss += v[i]*v[i]; }
#pragma unroll
  for (int o = 16; o; o >>= 1) { s += __shfl_xor(s, o, 64); ss += __shfl_xor(ss, o, 64); }
  float m = s * (1.f/256.f);
  float var = ss * (1.f/256.f) - m*m;
  float r = rsqrtf(var + 1e-5f);
#pragma unroll
  for (int i = 0; i < 8; ++i) v[i] = (v[i]-m)*r;
}

__device__ __forceinline__ void ldcvt8(const __bf16* p, float* v) {
  bf16x8 t = *reinterpret_cast<const bf16x8*>(p);
#pragma unroll
  for (int i = 0; i < 8; ++i) v[i] = (float)t[i];
}
__device__ __forceinline__ void stb8(__bf16* p, const float* v) {
  bf16x8 o8;
#pragma unroll
  for (int i = 0; i < 8; ++i) o8[i] = (__bf16)v[i];
  *reinterpret_cast<bf16x8*>(p) = o8;
}

// ---------------- fp32 -> bf16 converter (weights + embeddings, 19 jobs) ----------------
struct CPack { const float* src[19]; __bf16* dst[19]; int n[19]; };
__global__ __launch_bounds__(256) void convert_all(CPack p) {
  const int wi = blockIdx.y;
  const int n = p.n[wi];
  const float* s = p.src[wi];
  __bf16* d = p.dst[wi];
  for (int i = (blockIdx.x * 256 + threadIdx.x) * 4; i < n; i += gridDim.x * 256 * 4) {
    f4 v = ld4(s + i);
    stb4(d + i, v);
  }
}

// ---------------- contention-free two-level counting-sort CSR build ----------------
struct GPack {
  const int* src[4]; const int* dst[4]; int nE[4];
  int* col[4]; int* rowptr[4]; float* outdeg[4];  // dinvP,dinvD,icD,icP
  unsigned* stg[4];
  int* bh;      // [4][NBUCK][NBLKMAX]
  int* bbase;   // [4][NBUCK+1]
};

__global__ __launch_bounds__(256) void sort_hist(GPack g) {
  __shared__ int h[NBUCK];
  const int gi = blockIdx.y, blk = blockIdx.x;
  const int t = threadIdx.x;
  for (int i = t; i < NBUCK; i += 256) h[i] = 0;
  __syncthreads();
  const int base = blk * CH, nE = g.nE[gi];
  const int* dst = g.dst[gi];
#pragma unroll
  for (int i = 0; i < CH / 256; ++i) {
    int e = base + i * 256 + t;
    if (e < nE) atomicAdd(&h[dst[e] >> 7], 1);
  }
  __syncthreads();
  int* bh = g.bh + (size_t)gi * NBUCK * NBLKMAX;
  for (int i = t; i < NBUCK; i += 256) bh[i * NBLKMAX + blk] = h[i];
}

__global__ __launch_bounds__(1024) void sort_scan(GPack g) {
  __shared__ int sums[1024];
  const int gi = blockIdx.y;
  int* bh = g.bh + (size_t)gi * NBUCK * NBLKMAX;
  int* bbase = g.bbase + gi * (NBUCK + 1);
  const int L = NBUCK * NBLKMAX;
  const int t = threadIdx.x;
  const int chunk = (L + 1023) / 1024;
  const int b = t * chunk;
  const int e = min(b + chunk, L);
  int s = 0;
  for (int i = b; i < e; ++i) s += bh[i];
  sums[t] = s;
  __syncthreads();
  for (int o = 1; o < 1024; o <<= 1) {
    int u = (t >= o) ? sums[t - o] : 0;
    __syncthreads();
    sums[t] += u;
    __syncthreads();
  }
  int run = sums[t] - s;
  for (int i = b; i < e; ++i) {
    if (i % NBLKMAX == 0) bbase[i / NBLKMAX] = run;
    int old = bh[i];
    bh[i] = run;
    run += old;
  }
  if (t == 0) bbase[NBUCK] = g.nE[gi];
}

__global__ __launch_bounds__(256) void sort_scatter(GPack g) {
  __shared__ int cur[NBUCK];
  const int gi = blockIdx.y, blk = blockIdx.x;
  const int t = threadIdx.x;
  const int* bh = g.bh + (size_t)gi * NBUCK * NBLKMAX;
  for (int i = t; i < NBUCK; i += 256) cur[i] = bh[i * NBLKMAX + blk];
  __syncthreads();
  const int base = blk * CH, nE = g.nE[gi];
  const int* src = g.src[gi];
  const int* dst = g.dst[gi];
  unsigned* stg = g.stg[gi];
#pragma unroll
  for (int i = 0; i < CH / 256; ++i) {
    int e = base + i * 256 + t;
    if (e < nE) {
      int d = dst[e];
      int bkt = d >> 7;
      int pos = atomicAdd(&cur[bkt], 1);
      stg[pos] = ((unsigned)src[e] << 7) | (unsigned)(d & 127);
    }
  }
}

__global__ __launch_bounds__(256) void bucket_csr(GPack g) {
  const int gi = blockIdx.y;
  const int b = blockIdx.x;
  const int base = g.bbase[gi * (NBUCK + 1) + b];
  const int cnt  = g.bbase[gi * (NBUCK + 1) + b + 1] - base;
  __shared__ int h[RPB], sc[RPB];
  const int t = threadIdx.x;
  if (t < RPB) h[t] = 0;
  __syncthreads();
  const unsigned* st = g.stg[gi] + base;
  const int row0 = b * RPB;
  for (int i = t; i < cnt; i += 256) atomicAdd(&h[st[i] & 127u], 1);
  __syncthreads();
  if (t == 0) { int run = 0; for (int r = 0; r < RPB; ++r) { sc[r] = run; run += h[r]; } }
  __syncthreads();
  const int rows = min(RPB, PN - row0);
  if (t < rows) {
    g.rowptr[gi][row0 + t] = base + sc[t];
    float c = (float)h[t];
    g.outdeg[gi][row0 + t] = (gi < 2) ? rsqrtf(c + 1.f) : (1.f / fmaxf(c, 1.f));
  }
  if (b == 0 && t == 0) g.rowptr[gi][PN] = g.nE[gi];
  __syncthreads();
  if (t < RPB) h[t] = sc[t];
  __syncthreads();
  for (int i = t; i < cnt; i += 256) {
    unsigned v = st[i];
    int pos = atomicAdd(&h[v & 127u], 1);
    g.col[gi][base + pos] = (int)(v >> 7);
  }
}

// ---------------- batched GEMM v4: LDS-staged X tile; wave computes 64x64 ----------------
struct GB {
  const __bf16* X[6]; int lda[6];
  const __bf16* Wt[6]; const float* bias[6]; const float* scale[6];
  __bf16* out[6]; int K[6]; int ostride[6]; int act[6]; int ncol[6];  // ncol = N/256
};

__global__ __launch_bounds__(256) void gemm_batch(GB gb) {
  __shared__ __bf16 XS[64][XPAD];
  const int y = blockIdx.y;
  const int colchunk = gb.ncol[y];
  const int bid = blockIdx.x;
  if (bid >= 8 * RBX * colchunk) return;
  const int xcd = bid & 7;
  const int j = bid >> 3;
  const int row_blk = xcd * RBX + j / colchunk;
  const int cc = j % colchunk;
  const int M = PN;
  if (row_blk * 64 >= M) return;

  const __bf16* X  = gb.X[y];
  const __bf16* Wt = gb.Wt[y];
  const float* bias = gb.bias[y];
  const float* scale = gb.scale[y];
  __bf16* outb = gb.out[y];
  const int lda = gb.lda[y];
  const int K = gb.K[y];
  const int ostride = gb.ostride[y];
  const int act = gb.act[y];

  const int tid = threadIdx.x;
  const int lane = tid & 63;
  const int w = tid >> 6;
  const int r0 = row_blk * 64;
  const int c0 = cc * 256 + w * 64;
  const int l15 = lane & 15;
  const int lk = (lane >> 4) * 8;

  f32x4v acc[4][4];
#pragma unroll
  for (int m = 0; m < 4; ++m)
#pragma unroll
    for (int n = 0; n < 4; ++n) { acc[m][n][0]=0.f; acc[m][n][1]=0.f; acc[m][n][2]=0.f; acc[m][n][3]=0.f; }

  const __bf16* wp[4];
#pragma unroll
  for (int n = 0; n < 4; ++n) {
    wp[n] = Wt + (size_t)(c0 + n * 16 + l15) * K + lk;
  }

  const int srow = tid >> 5;   // 0..7
  const int sseg = tid & 31;   // 0..31 (16B segments per 512B row-chunk)

  for (int kc = 0; kc < K; kc += KT) {
    if (kc) __syncthreads();   // protect XS reuse across chunks
    // stage X[r0..r0+63][kc..kc+KT) -> XS (coalesced 512B per row)
#pragma unroll
    for (int it = 0; it < 8; ++it) {
      int rl = it * 8 + srow;
      int rg = min(r0 + rl, M - 1);
      bf16x8 v = *reinterpret_cast<const bf16x8*>(X + (size_t)rg * lda + kc + sseg * 8);
      *reinterpret_cast<bf16x8*>(&XS[rl][sseg * 8]) = v;
    }
    __syncthreads();

#pragma unroll 2
    for (int k0 = 0; k0 < KT; k0 += 32) {
      bf16x8 a[4], b[4];
#pragma unroll
      for (int m = 0; m < 4; ++m)
        a[m] = *reinterpret_cast<const bf16x8*>(&XS[m * 16 + l15][k0 + lk]);
#pragma unroll
      for (int n = 0; n < 4; ++n)
        b[n] = *reinterpret_cast<const bf16x8*>(wp[n] + kc + k0);
#pragma unroll
      for (int m = 0; m < 4; ++m)
#pragma unroll
        for (int n = 0; n < 4; ++n)
          acc[m][n] = __builtin_amdgcn_mfma_f32_16x16x32_bf16(a[m], b[n], acc[m][n], 0, 0, 0);
    }
  }

  const int rq = (lane >> 4) * 4;
#pragma unroll
  for (int m = 0; m < 4; ++m) {
#pragma unroll
    for (int i = 0; i < 4; ++i) {
      int row = r0 + m * 16 + rq + i;
      if (row >= M) continue;
#pragma unroll
      for (int n = 0; n < 4; ++n) {
        int col = c0 + n * 16 + l15;
        float v = acc[m][n][i];
        if (bias) v += bias[col];
        if (act == 1) v = fmaxf(v, 0.f);
        else if (act == 2) v = v > 0.f ? v : (expf(v) - 1.f);
        if (scale && col < 256) v *= scale[row];
        outb[(size_t)row * ostride + col] = (__bf16)v;
      }
    }
  }
}

// ---------------- batched fused GCN stage, half-wave per row (mode 0) / ln_elu (mode 1) ----
struct SB {
  const int* rpG[4]; const int* clG[4]; const float* dinv[4];
  const __bf16* T[4]; int tstr[4];
  const float* gbias[4]; const float* linb[4];
  const int* rpS[4]; const int* clS[4]; const float* ic[4]; const __bf16* Pt[4];
  const float* lw[4]; const float* lb[4];
  __bf16* out[4]; int ostr[4]; int n[4]; int act[4]; int mode[4];
};

__global__ __launch_bounds__(256) void stage_batch(SB sb) {
  const int y = blockIdx.y;
  int row = (blockIdx.x * 256 + threadIdx.x) >> 5;
  if (row >= sb.n[y]) return;
  int l = threadIdx.x & 31;
  int o = l * 8;
  const __bf16* T = sb.T[y];
  const int tstr = sb.tstr[y];
  __bf16* out = sb.out[y];
  const int ostr = sb.ostr[y];

  float x[8];

  if (sb.mode[y] == 1) {   // fp = elu(LN(T_row))
    ldcvt8(T + (size_t)row * tstr + o, x);
    ln8(x);
#pragma unroll
    for (int i = 0; i < 8; ++i) x[i] = x[i] > 0.f ? x[i] : expf(x[i]) - 1.f;
    stb8(out + (size_t)row * ostr + o, x);
    return;
  }

  const int* rpG = sb.rpG[y];
  const int* clG = sb.clG[y];
  const float* dinv = sb.dinv[y];
  float dd = dinv[row];

  // T is pre-scaled by dinv (t' rows); g = self + neighbors; x = dd*g.
  float g[8];
  ldcvt8(T + (size_t)row * tstr + o, g);

  int beg = rpG[row], end = rpG[row + 1];
  int j = beg;
  for (; j + 7 < end; j += 8) {
    int s[8];
    bf16x8 tv[8];
#pragma unroll
    for (int q = 0; q < 8; ++q) s[q] = clG[j + q];
#pragma unroll
    for (int q = 0; q < 8; ++q) tv[q] = *reinterpret_cast<const bf16x8*>(T + (size_t)s[q] * tstr + o);
#pragma unroll
    for (int q = 0; q < 8; ++q)
#pragma unroll
      for (int i = 0; i < 8; ++i) g[i] += (float)tv[q][i];
  }
  for (; j < end; ++j) {
    bf16x8 tv = *reinterpret_cast<const bf16x8*>(T + (size_t)clG[j] * tstr + o);
#pragma unroll
    for (int i = 0; i < 8; ++i) g[i] += (float)tv[i];
  }

#pragma unroll
  for (int i = 0; i < 8; ++i) x[i] = g[i] * dd;

  if (sb.gbias[y]) {
    f4 b0 = ld4(sb.gbias[y] + o), b1 = ld4(sb.gbias[y] + o + 4);
    x[0]+=b0.x; x[1]+=b0.y; x[2]+=b0.z; x[3]+=b0.w;
    x[4]+=b1.x; x[5]+=b1.y; x[6]+=b1.z; x[7]+=b1.w;
  }
  if (sb.linb[y]) {
    f4 b0 = ld4(sb.linb[y] + o), b1 = ld4(sb.linb[y] + o + 4);
    x[0]+=b0.x; x[1]+=b0.y; x[2]+=b0.z; x[3]+=b0.w;
    x[4]+=b1.x; x[5]+=b1.y; x[6]+=b1.z; x[7]+=b1.w;
  }
  {
    bf16x8 lv = *reinterpret_cast<const bf16x8*>(T + (size_t)row * tstr + 256 + o);
#pragma unroll
    for (int i = 0; i < 8; ++i) x[i] += (float)lv[i];
  }

  if (sb.rpS[y]) {
    const int* rpS = sb.rpS[y];
    const int* clS = sb.clS[y];
    const __bf16* Pt = sb.Pt[y];
    float s8[8];
#pragma unroll
    for (int i = 0; i < 8; ++i) s8[i] = 0.f;
    int sbg = rpS[row], se = rpS[row + 1];
    int k = sbg;
    for (; k + 7 < se; k += 8) {
      int s[8];
      bf16x8 tv[8];
#pragma unroll
      for (int q = 0; q < 8; ++q) s[q] = clS[k + q];
#pragma unroll
      for (int q = 0; q < 8; ++q) tv[q] = *reinterpret_cast<const bf16x8*>(Pt + (size_t)s[q] * 256 + o);
#pragma unroll
      for (int q = 0; q < 8; ++q)
#pragma unroll
        for (int i = 0; i < 8; ++i) s8[i] += (float)tv[q][i];
    }
    for (; k < se; ++k) {
      bf16x8 tv = *reinterpret_cast<const bf16x8*>(Pt + (size_t)clS[k] * 256 + o);
#pragma unroll
      for (int i = 0; i < 8; ++i) s8[i] += (float)tv[i];
    }
    float icv = sb.ic[y][row];
#pragma unroll
    for (int i = 0; i < 8; ++i) x[i] += s8[i] * icv;
  }

  ln8(x);
  if (sb.lw[y]) {
    f4 w0 = ld4(sb.lw[y] + o), w1 = ld4(sb.lw[y] + o + 4);
    f4 c0 = ld4(sb.lb[y] + o), c1 = ld4(sb.lb[y] + o + 4);
    x[0]=x[0]*w0.x+c0.x; x[1]=x[1]*w0.y+c0.y; x[2]=x[2]*w0.z+c0.z; x[3]=x[3]*w0.w+c0.w;
    x[4]=x[4]*w1.x+c1.x; x[5]=x[5]*w1.y+c1.y; x[6]=x[6]*w1.z+c1.z; x[7]=x[7]*w1.w+c1.w;
  }
  if (sb.act[y] == 1) {
#pragma unroll
    for (int i = 0; i < 8; ++i) x[i] = fmaxf(x[i], 0.f);
  }
  stb8(out + (size_t)row * ostr + o, x);
}

// ---------------- pair epilogue: one pair per 32-lane half-wave ----------------
__global__ __launch_bounds__(256) void pair_kernel(
    const __bf16* __restrict__ PK,
    const int* __restrict__ idx1, const int* __restrict__ idx2,
    const float* __restrict__ wR, const float* __restrict__ wI,
    float* __restrict__ out, int npair)
{
  int pid = (blockIdx.x * 256 + threadIdx.x) >> 5;
  if (pid >= npair) return;
  int l = threadIdx.x & 31;
  int f = l * 8;
  const __bf16* r1 = PK + (size_t)idx1[pid] * 1024;
  const __bf16* r2 = PK + (size_t)idx2[pid] * 1024;

  bf16x8 a0 = *reinterpret_cast<const bf16x8*>(r1 + f);
  bf16x8 a1 = *reinterpret_cast<const bf16x8*>(r1 + 256 + f);
  bf16x8 a2 = *reinterpret_cast<const bf16x8*>(r1 + 512 + f);
  bf16x8 a3 = *reinterpret_cast<const bf16x8*>(r1 + 768 + f);
  bf16x8 b0 = *reinterpret_cast<const bf16x8*>(r2 + f);
  bf16x8 b1 = *reinterpret_cast<const bf16x8*>(r2 + 256 + f);
  bf16x8 b2 = *reinterpret_cast<const bf16x8*>(r2 + 512 + f);
  bf16x8 b3 = *reinterpret_cast<const bf16x8*>(r2 + 768 + f);

  float R1[8], I1[8], R2[8], I2[8];
#pragma unroll
  for (int i = 0; i < 8; ++i) {
    R1[i] = (float)a0[i] + (float)b1[i];
    I1[i] = (float)a2[i] + (float)b3[i];
    R2[i] = (float)a3[i] + (float)b2[i];
    I2[i] = (float)a1[i] + (float)b0[i];
  }
  ln8(R1); ln8(I1); ln8(R2); ln8(I2);

  float R[8], I[8];
#pragma unroll
  for (int i = 0; i < 8; ++i) {
    R[i] = R1[i]*R2[i] - I1[i]*I2[i];
    I[i] = R1[i]*I2[i] + I1[i]*R2[i];
  }
  ln8(R); ln8(I);

  f4 wr0 = ld4(wR + f), wr1 = ld4(wR + f + 4);
  f4 wi0 = ld4(wI + f), wi1 = ld4(wI + f + 4);
  float wrv[8] = {wr0.x,wr0.y,wr0.z,wr0.w, wr1.x,wr1.y,wr1.z,wr1.w};
  float wiv[8] = {wi0.x,wi0.y,wi0.z,wi0.w, wi1.x,wi1.y,wi1.z,wi1.w};
  float t = 0.f;
#pragma unroll
  for (int i = 0; i < 8; ++i) t += R[i]*(wrv[i]-wiv[i]) + I[i]*(wrv[i]+wiv[i]);
#pragma unroll
  for (int o = 16; o; o >>= 1) t += __shfl_xor(t, o, 64);
  if (l == 0) out[pid] = 1.f / (1.f + expf(-t));
}

extern "C" void kernel_launch(void* const* d_in, const int* in_sizes, int n_in,
                              void* d_out, int out_size, void* d_ws, size_t ws_size,
                              hipStream_t stream) {
  (void)in_sizes; (void)n_in; (void)out_size; (void)ws_size;
  const float* seq        = (const float*)d_in[0];
  const int*   ppi        = (const int*)d_in[1];
  const int*   ddi        = (const int*)d_in[2];
  const int*   dti        = (const int*)d_in[3];
  const int*   idx1       = (const int*)d_in[4];
  const int*   idx2       = (const int*)d_in[5];
  const float* seq_init_W = (const float*)d_in[6];
  const float* gs1_gcn_W  = (const float*)d_in[7];
  const float* gs1_gcn_b  = (const float*)d_in[8];
  const float* gs1_lin_W  = (const float*)d_in[9];
  const float* gs1_ln_w   = (const float*)d_in[10];
  const float* gs1_ln_b   = (const float*)d_in[11];
  const float* gs2_gcn_W  = (const float*)d_in[12];
  const float* gs2_gcn_b  = (const float*)d_in[13];
  const float* gs2_lin_W  = (const float*)d_in[14];
  const float* gs2_ln_w   = (const float*)d_in[15];
  const float* gs2_ln_b   = (const float*)d_in[16];
  const float* drug_emb   = (const float*)d_in[17];
  const float* prot_emb   = (const float*)d_in[18];
  const float* pp1_W = (const float*)d_in[19]; const float* pp1_b = (const float*)d_in[20];
  const float* td1_W = (const float*)d_in[21]; const float* td1_b = (const float*)d_in[22];
  const float* pr1_W = (const float*)d_in[23]; const float* pr1_b = (const float*)d_in[24];
  const float* dd1_W = (const float*)d_in[25]; const float* dd1_b = (const float*)d_in[26];
  const float* dt1_W = (const float*)d_in[27]; const float* dt1_b = (const float*)d_in[28];
  const float* dr1_W = (const float*)d_in[29]; const float* dr1_b = (const float*)d_in[30];
  const float* pp2_W = (const float*)d_in[31]; const float* pp2_b = (const float*)d_in[32];
  const float* td2_W = (const float*)d_in[33]; const float* td2_b = (const float*)d_in[34];
  const float* pr2_W = (const float*)d_in[35]; const float* pr2_b = (const float*)d_in[36];
  const float* seq_fc_W  = (const float*)d_in[43];
  const float* skip_fc_W = (const float*)d_in[44];
  const float* wR = (const float*)d_in[45];
  const float* wI = (const float*)d_in[46];
  float* outp = (float*)d_out;

  // ---------------- workspace layout ----------------
  char* base = (char*)d_ws;
  unsigned* stgP  = (unsigned*)base;                 // EPPI
  unsigned* stgD  = stgP + EPPI;
  unsigned* stgTD = stgD + EDDI;
  unsigned* stgTP = stgTD + EDTI;
  int* colP  = (int*)(stgTP + EDTI);
  int* colD  = colP + EPPI;
  int* colTD = colD + EDDI;
  int* colTP = colTD + EDTI;
  int* rowptrP  = colTP + EDTI;
  int* rowptrD  = rowptrP + PN + 1;
  int* rowptrTD = rowptrD + PN + 1;
  int* rowptrTP = rowptrTD + PN + 1;
  float* dinvP = (float*)(rowptrTP + PN + 1);
  float* dinvD = dinvP + PN;
  float* icD   = dinvD + PN;
  float* icP   = icD + PN;
  int* bh    = (int*)(icP + PN);                     // 4*NBUCK*NBLKMAX
  int* bbase = bh + 4 * NBUCK * NBLKMAX;             // 4*(NBUCK+1)

  unsigned long long waddr = (unsigned long long)(bbase + 4 * (NBUCK + 1));
  waddr = (waddr + 63ULL) & ~63ULL;
  __bf16* wb = (__bf16*)waddr;
  __bf16* Wseq  = wb;                           // [256,1024]
  __bf16* pair0 = Wseq + 256*1024;              // each pair [512,256]
  __bf16* pair1 = pair0 + 512*256;
  __bf16* pair2 = pair1 + 512*256;
  __bf16* pair3 = pair2 + 512*256;
  __bf16* pair4 = pair3 + 512*256;
  __bf16* sing  = pair4 + 512*256;
  __bf16* Wdt1  = sing;
  __bf16* Wtd1  = sing + 65536;
  __bf16* Wtd2  = sing + 2*65536;
  __bf16* Wsfc  = sing + 3*65536;
  __bf16* Wskp  = sing + 4*65536;
  const size_t NB = (size_t)PN * 256;
  __bf16* Ed    = sing + 5*65536;               // [20000,256]
  __bf16* Ep    = Ed + NB;
  __bf16* TL0   = Ep + NB;                      // [20000,512]
  __bf16* TLd   = TL0 + (size_t)PN*512;         // [20000,512]
  __bf16* TLp   = TLd + (size_t)PN*512;         // [20000,512]
  __bf16* B0    = TLp + (size_t)PN*512;         // x_seq
  __bf16* Bh    = B0 + NB;                      // h
  __bf16* B4a   = Bh + NB;                      // proj_p (4d) -> P5 proj
  __bf16* B4b   = B4a + NB;                     // proj_d (4p)
  __bf16* B4e   = B4b + NB;                     // fp
  __bf16* PK    = B4e + NB;                     // [20000][1024]: x1 | xfp | p2 | xskip
  __bf16* Eseq  = PK;                           // alias, dead after G1
  __bf16* Bd    = PK + 0;                       // d, stride 1024 (slot0)
  __bf16* Bp    = PK + 512;                     // p, stride 1024 (slot2)

  const dim3 blk(256);
  const dim3 sgrid(NBLKMAX, 4);
  const dim3 bgrid(NBUCK, 4);
  const int SROWS = (PN + 7) / 8;      // 2500 blocks for half-wave stage jobs
  const int GMAX  = 8 * RBX * 2;       // 640 blocks for colchunk<=2 gemm

  // ---- converts (1 launch, 19 jobs) ----
  {
    CPack p;
    const float* srcs[19] = { seq_init_W, gs1_gcn_W, gs1_lin_W, gs2_gcn_W, gs2_lin_W,
                              dd1_W, dr1_W, pp1_W, pr1_W, pp2_W, pr2_W,
                              dt1_W, td1_W, td2_W, seq_fc_W, skip_fc_W,
                              seq, drug_emb, prot_emb };
    __bf16* dsts[19] = { Wseq, pair0, pair0 + 65536, pair1, pair1 + 65536,
                         pair2, pair2 + 65536, pair3, pair3 + 65536, pair4, pair4 + 65536,
                         Wdt1, Wtd1, Wtd2, Wsfc, Wskp,
                         Eseq, Ed, Ep };
    for (int i = 0; i < 19; ++i) {
      p.src[i] = srcs[i]; p.dst[i] = dsts[i];
      p.n[i] = (i == 0) ? 256*1024 : (i == 16) ? PN*SEQK : (i >= 17) ? PN*256 : 256*256;
    }
    hipLaunchKernelGGL(convert_all, dim3(2048, 19), blk, 0, stream, p);
  }

  // ---- counting-sort CSR build ----
  GPack g;
  g.src[0] = ppi;        g.dst[0] = ppi + EPPI; g.nE[0] = EPPI;
  g.src[1] = ddi;        g.dst[1] = ddi + EDDI; g.nE[1] = EDDI;
  g.src[2] = dti + EDTI; g.dst[2] = dti;        g.nE[2] = EDTI;
  g.src[3] = dti;        g.dst[3] = dti + EDTI; g.nE[3] = EDTI;
  g.col[0] = colP;  g.col[1] = colD;  g.col[2] = colTD;  g.col[3] = colTP;
  g.rowptr[0] = rowptrP; g.rowptr[1] = rowptrD; g.rowptr[2] = rowptrTD; g.rowptr[3] = rowptrTP;
  g.outdeg[0] = dinvP; g.outdeg[1] = dinvD; g.outdeg[2] = icD; g.outdeg[3] = icP;
  g.stg[0] = stgP; g.stg[1] = stgD; g.stg[2] = stgTD; g.stg[3] = stgTP;
  g.bh = bh; g.bbase = bbase;

  hipLaunchKernelGGL(sort_hist,    sgrid, blk, 0, stream, g);
  hipLaunchKernelGGL(sort_scan,    dim3(1, 4), dim3(1024), 0, stream, g);
  hipLaunchKernelGGL(sort_scatter, sgrid, blk, 0, stream, g);
  hipLaunchKernelGGL(bucket_csr,   bgrid, blk, 0, stream, g);

  auto GJOB = [&](GB& b, int i, const __bf16* X, int lda, const __bf16* Wt, const float* bias,
                  const float* scale, __bf16* out, int K, int ostr, int act, int colchunk) {
    b.X[i]=X; b.lda[i]=lda; b.Wt[i]=Wt; b.bias[i]=bias; b.scale[i]=scale;
    b.out[i]=out; b.K[i]=K; b.ostride[i]=ostr; b.act[i]=act; b.ncol[i]=colchunk;
  };
  auto SJOB = [&](SB& s, int i, const int* rpG, const int* clG, const float* dv,
                  const __bf16* T, int tstr, const float* gb, const float* lnb,
                  const int* rpS, const int* clS, const float* ic, const __bf16* Pt,
                  const float* lw, const float* lb, __bf16* out, int ostr, int n, int act) {
    s.mode[i]=0; s.rpG[i]=rpG; s.clG[i]=clG; s.dinv[i]=dv; s.T[i]=T; s.tstr[i]=tstr;
    s.gbias[i]=gb; s.linb[i]=lnb; s.rpS[i]=rpS; s.clS[i]=clS; s.ic[i]=ic; s.Pt[i]=Pt;
    s.lw[i]=lw; s.lb[i]=lb; s.out[i]=out; s.ostr[i]=ostr; s.n[i]=n; s.act[i]=act;
  };
  auto LJOB = [&](SB& s, int i, const __bf16* T, int tstr, __bf16* out, int ostr, int n) {
    s.mode[i]=1; s.T[i]=T; s.tstr[i]=tstr; s.out[i]=out; s.ostr[i]=ostr; s.n[i]=n;
  };

  // ---- G1: 6 GEMMs (P1, 4d-t, 4d-proj, 4p-t, 4p-proj, xskip) ----
  {
    GB b{};
    GJOB(b, 0, Eseq, 1024, Wseq,  nullptr, nullptr, B0,       1024, 256,  1, 1);
    GJOB(b, 1, Ed,   256,  pair2, nullptr, dinvD,   TLd,      256,  512,  0, 2);
    GJOB(b, 2, Ep,   256,  Wdt1,  dt1_b,   nullptr, B4a,      256,  256,  0, 1);
    GJOB(b, 3, Ep,   256,  pair3, nullptr, dinvP,   TLp,      256,  512,  0, 2);
    GJOB(b, 4, Ed,   256,  Wtd1,  td1_b,   nullptr, B4b,      256,  256,  0, 1);
    GJOB(b, 5, Ep,   256,  Wskp,  nullptr, nullptr, PK + 768, 256,  1024, 0, 1);
    hipLaunchKernelGGL(gemm_batch, dim3(GMAX, 6), blk, 0, stream, b);
  }

  // ---- G2: 1 GEMM (P2-t) ----
  {
    GB b{};
    GJOB(b, 0, B0, 256, pair0, nullptr, dinvP, TL0, 256, 512, 0, 2);
    hipLaunchKernelGGL(gemm_batch, dim3(GMAX, 1), blk, 0, stream, b);
  }

  // ---- S1: stage{4d -> Bd, 4p -> Bp, gs1 -> Bh} + ln_elu{B0 -> B4e} ----
  {
    SB s{};
    SJOB(s, 0, rowptrD, colD, dinvD, TLd, 512, dd1_b, dr1_b,
         rowptrTD, colTD, icD, B4a, nullptr, nullptr, Bd, 1024, DN, 1);
    SJOB(s, 1, rowptrP, colP, dinvP, TLp, 512, pp1_b, pr1_b,
         rowptrTP, colTP, icP, B4b, nullptr, nullptr, Bp, 1024, PN, 1);
    SJOB(s, 2, rowptrP, colP, dinvP, TL0, 512, gs1_gcn_b, nullptr,
         nullptr, nullptr, nullptr, nullptr, gs1_ln_w, gs1_ln_b, Bh, 256, PN, 1);
    LJOB(s, 3, B0, 256, B4e, 256, PN);
    hipLaunchKernelGGL(stage_batch, dim3(SROWS, 4), blk, 0, stream, s);
  }

  // ---- G3: 4 GEMMs (P3-t, P5-t, P5-proj, xfp) ----
  {
    GB b{};
    GJOB(b, 0, Bh,  256,  pair1, nullptr, dinvP,   TLd,      256, 512,  0, 2);
    GJOB(b, 1, Bp,  1024, pair4, nullptr, dinvP,   TLp,      256, 512,  0, 2);
    GJOB(b, 2, Bd,  1024, Wtd2,  td2_b,   nullptr, B4a,      256, 256,  0, 1);
    GJOB(b, 3, B4e, 256,  Wsfc,  nullptr, nullptr, PK + 256, 256, 1024, 2, 1);
    hipLaunchKernelGGL(gemm_batch, dim3(GMAX, 4), blk, 0, stream, b);
  }

  // ---- S2: stage{gs2 -> PK slot0, P5 -> PK slot2} ----
  {
    SB s{};
    SJOB(s, 0, rowptrP, colP, dinvP, TLd, 512, gs2_gcn_b, nullptr,
         nullptr, nullptr, nullptr, nullptr, gs2_ln_w, gs2_ln_b, PK + 0, 1024, PN, 0);
    SJOB(s, 1, rowptrP, colP, dinvP, TLp, 512, pp2_b, pr2_b,
         rowptrTP, colTP, icP, B4a, nullptr, nullptr, PK + 512, 1024, PN, 0);
    hipLaunchKernelGGL(stage_batch, dim3(SROWS, 2), blk, 0, stream, s);
  }

  // ---- pair epilogue ----
  hipLaunchKernelGGL(pair_kernel, dim3((NPAIRN + 7) / 8), blk, 0, stream,
                     PK, idx1, idx2, wR, wI, outp, NPAIRN);
}